// Round 4
// baseline (2283.425 us; speedup 1.0000x reference)
//
#include <hip/hip_runtime.h>
#include <math.h>

// Problem dims
#define NB   16     // batch
#define SL   128    // seq len
#define ED   300    // word emb dim
#define HD   512    // lstm hidden
#define G4   2048   // 4*HD
#define NT   9      // tag count T
#define BE   64     // bio emb dim
#define RE   128    // REL_E
#define NR   50     // R
#define OCD  576    // HD + BE
#define NTOK 2048   // NB*SL

__device__ __forceinline__ float sigf(float x){ return 1.0f/(1.0f + __expf(-x)); }

// ---------------------------------------------------------------- gather emb
__global__ __launch_bounds__(256) void gather_emb_k(const int* __restrict__ tokens,
                                                    const float* __restrict__ word_emb,
                                                    float* __restrict__ emb)
{
    int idx = blockIdx.x*256 + threadIdx.x;
    if (idx < NTOK*ED){
        int row = idx / ED;
        int k = idx - row*ED;
        emb[idx] = word_emb[tokens[row]*ED + k];
    }
}

// ---------------------------------------------------------------- generic fp32 GEMM
// C[m,n] = act( sum_k A[m,k]*B[n,k] + bias1[n] + bias2[n] )
template<int TM>
__global__ __launch_bounds__(256) void gemm_k(const float* __restrict__ A, int lda,
                                              const float* __restrict__ Bm, int ldb,
                                              float* __restrict__ C, int ldc,
                                              int N, int K,
                                              const float* __restrict__ bias1,
                                              const float* __restrict__ bias2,
                                              int do_relu)
{
    constexpr int TR = TM/16;                 // rows per thread (8 or 4)
    __shared__ float As[16][TM+4];            // [k][m]
    __shared__ float Bs[16][68];              // [k][n]
    const int t = threadIdx.x;
    const int m_blk = blockIdx.x * TM;
    const int n_blk = blockIdx.y * 64;
    const int tm = (t >> 4) * TR;
    const int tn = (t & 15) * 4;
    float acc[TR][4];
    #pragma unroll
    for (int i=0;i<TR;++i){ acc[i][0]=0.f; acc[i][1]=0.f; acc[i][2]=0.f; acc[i][3]=0.f; }

    const int kc = (K + 15) >> 4;
    for (int ck = 0; ck < kc; ++ck){
        const int k0 = ck << 4;
        __syncthreads();
        #pragma unroll
        for (int it = 0; it < TM/64; ++it){
            int task = t + it*256;
            int m = task >> 2, q = task & 3;
            int kk = k0 + q*4;
            float4 v = make_float4(0.f,0.f,0.f,0.f);
            const float* ap = A + (size_t)(m_blk + m)*lda + kk;
            if (kk + 3 < K) v = *(const float4*)ap;
            else {
                if (kk   < K) v.x = ap[0];
                if (kk+1 < K) v.y = ap[1];
                if (kk+2 < K) v.z = ap[2];
            }
            As[q*4+0][m] = v.x; As[q*4+1][m] = v.y; As[q*4+2][m] = v.z; As[q*4+3][m] = v.w;
        }
        {
            int n = t >> 2, q = t & 3;
            int kk = k0 + q*4;
            int gn = n_blk + n;
            float4 v = make_float4(0.f,0.f,0.f,0.f);
            if (gn < N){
                const float* bp = Bm + (size_t)gn*ldb + kk;
                if (kk + 3 < K) v = *(const float4*)bp;
                else {
                    if (kk   < K) v.x = bp[0];
                    if (kk+1 < K) v.y = bp[1];
                    if (kk+2 < K) v.z = bp[2];
                }
            }
            Bs[q*4+0][n] = v.x; Bs[q*4+1][n] = v.y; Bs[q*4+2][n] = v.z; Bs[q*4+3][n] = v.w;
        }
        __syncthreads();
        #pragma unroll
        for (int k = 0; k < 16; ++k){
            float4 b4 = *(const float4*)&Bs[k][tn];
            float bn[4] = {b4.x, b4.y, b4.z, b4.w};
            #pragma unroll
            for (int i = 0; i < TR/4; ++i){
                float4 a4 = *(const float4*)&As[k][tm + i*4];
                float am[4] = {a4.x, a4.y, a4.z, a4.w};
                #pragma unroll
                for (int mm = 0; mm < 4; ++mm){
                    #pragma unroll
                    for (int nn = 0; nn < 4; ++nn)
                        acc[i*4+mm][nn] += am[mm]*bn[nn];
                }
            }
        }
    }
    float bv[4];
    #pragma unroll
    for (int nn=0;nn<4;++nn){
        int gn = n_blk + tn + nn;
        float bb = 0.f;
        if (gn < N){
            if (bias1) bb += bias1[gn];
            if (bias2) bb += bias2[gn];
        }
        bv[nn] = bb;
    }
    bool vec = ((ldc & 3) == 0) && (n_blk + tn + 3 < N);
    #pragma unroll
    for (int mm = 0; mm < TR; ++mm){
        int gm = m_blk + tm + mm;
        float r0 = acc[mm][0] + bv[0];
        float r1 = acc[mm][1] + bv[1];
        float r2 = acc[mm][2] + bv[2];
        float r3 = acc[mm][3] + bv[3];
        if (do_relu){ r0=fmaxf(r0,0.f); r1=fmaxf(r1,0.f); r2=fmaxf(r2,0.f); r3=fmaxf(r3,0.f); }
        if (vec){
            *(float4*)(C + (size_t)gm*ldc + n_blk + tn) = make_float4(r0,r1,r2,r3);
        } else {
            int gn = n_blk + tn;
            if (gn   < N) C[(size_t)gm*ldc + gn  ] = r0;
            if (gn+1 < N) C[(size_t)gm*ldc + gn+1] = r1;
            if (gn+2 < N) C[(size_t)gm*ldc + gn+2] = r2;
            if (gn+3 < N) C[(size_t)gm*ldc + gn+3] = r3;
        }
    }
}

// ---------------------------------------------------------------- team-parallel LSTM
// 8 independent teams of 32 wgs; team = (dir = team&1, batches [(team>>1)*4, +4)).
// wg rank owns hidden units [rank*16, +16) (64 gate rows); its 128KB weight slice
// lives in VGPRs -- __launch_bounds__(256,1) uncaps the allocator (R3's VGPR=60
// cap forced per-step weight re-reads = 966MB FETCH).
// SYNC IS FUSED INTO THE DATA: h is exchanged as packed u64 (tag<<32 | float_bits)
// relaxed agent atomics. Producer of h_{s+1} tags with (s+1); consumers at step s
// spin until their staged entries carry tag s. No flag barrier at all ->
// one LLC round-trip per step in the common case. Double-buffered by step parity
// (tag match makes parity reuse safe: a wg cannot be 2 steps ahead of any reader
// of the same parity).
__global__ __launch_bounds__(256, 1) void lstm_k(const float* __restrict__ xwf,
                                                 const float* __restrict__ xwb,
                                                 const float* __restrict__ whhf,
                                                 const float* __restrict__ whhb,
                                                 unsigned long long* __restrict__ hteam, // [8][2][2048] u64
                                                 float* __restrict__ hf_all,
                                                 float* __restrict__ hb_all)
{
    __shared__ __align__(16) float h_s[4*HD];      // 8 KB  [b][512]
    __shared__ __align__(16) float part[4*64*4];   // 4 KB  [kq][row][b]
    __shared__ float gates_s[64*4];                // [row][b]
    __shared__ float cst[64];                      // [b*16 + hl]
    const int wg   = blockIdx.x;
    const int team = wg >> 5;
    const int rank = wg & 31;
    const int d    = team & 1;
    const int b0   = (team >> 1) * 4;
    const int t    = threadIdx.x;
    const int kq   = t >> 6;                       // k-quarter (== wave id)
    const int rl   = t & 63;                       // local gate row 0..63
    const int grow = (rl >> 4)*HD + rank*16 + (rl & 15);   // global gate row
    const float* whh = d ? whhb : whhf;
    const float* xw  = d ? xwb  : xwf;
    float* hall      = d ? hb_all : hf_all;
    unsigned long long* hT = hteam + (size_t)team*2*(4*HD);

    // ---- one-time: weight slice into registers (32 float4 = 128 VGPRs) ----
    float4 w[32];
    {
        const float* wp = whh + (size_t)grow*HD + kq*128;
        #pragma unroll
        for (int q=0;q<32;++q) w[q] = *(const float4*)(wp + q*4);
    }
    // reduce mapping: t -> (row, batch)
    const int rrow = t >> 2, rb = t & 3;
    const int growr = (rrow >> 4)*HD + rank*16 + (rrow & 15);
    // activation mapping: t<64 -> (hidden-local, batch)
    const int ahl = t & 15, ab = t >> 4;
    const int hidx_a = rank*16 + ahl;

    if (t < 64) cst[t] = 0.f;
    __syncthreads();

    int par = 0;
    for (int s = 0; s < SL; ++s){
        const int tx = d ? (SL-1 - s) : s;
        // issue the xw read early (independent of staging; hides under the spin)
        const float xval = xw[(size_t)((b0 + rb)*SL + tx)*G4 + growr];
        // ---- 1. stage team h: spin on packed tags (tag == s), 8 u64/thread ----
        {
            const unsigned long long* src = hT + (size_t)par*(4*HD);
            float vals[8];
            unsigned done = 0;
            const unsigned want = (unsigned)s;
            for (;;){
                #pragma unroll
                for (int i = 0; i < 8; ++i){
                    if (!(done & (1u << i))){
                        unsigned long long v = __hip_atomic_load(&src[t + i*256],
                                                  __ATOMIC_RELAXED, __HIP_MEMORY_SCOPE_AGENT);
                        if ((unsigned)(v >> 32) == want){
                            vals[i] = __uint_as_float((unsigned)v);
                            done |= (1u << i);
                        }
                    }
                }
                if (done == 0xFFu) break;
                __builtin_amdgcn_s_sleep(1);
            }
            #pragma unroll
            for (int i = 0; i < 8; ++i) h_s[t + i*256] = vals[i];
        }
        __syncthreads();
        // ---- 2. partial dots: row rl, k-quarter kq, all 4 batches ----
        {
            float a0=0.f, a1=0.f, a2=0.f, a3=0.f;
            const float* hb_ = h_s + kq*128;       // wave-uniform base -> LDS broadcast
            #pragma unroll 8
            for (int q = 0; q < 32; ++q){
                float4 wq = w[q];
                float4 h0 = *(const float4*)(hb_ + 0*HD + q*4);
                float4 h1 = *(const float4*)(hb_ + 1*HD + q*4);
                float4 h2 = *(const float4*)(hb_ + 2*HD + q*4);
                float4 h3 = *(const float4*)(hb_ + 3*HD + q*4);
                a0 += wq.x*h0.x + wq.y*h0.y + wq.z*h0.z + wq.w*h0.w;
                a1 += wq.x*h1.x + wq.y*h1.y + wq.z*h1.z + wq.w*h1.w;
                a2 += wq.x*h2.x + wq.y*h2.y + wq.z*h2.z + wq.w*h2.w;
                a3 += wq.x*h3.x + wq.y*h3.y + wq.z*h3.z + wq.w*h3.w;
            }
            *(float4*)&part[(kq*64 + rl)*4] = make_float4(a0,a1,a2,a3);
        }
        __syncthreads();
        // ---- 3. reduce k-quarters + add xW (biases folded into xW) ----
        {
            float gsum = part[(0*64 + rrow)*4 + rb] + part[(1*64 + rrow)*4 + rb]
                       + part[(2*64 + rrow)*4 + rb] + part[(3*64 + rrow)*4 + rb];
            gates_s[rrow*4 + rb] = gsum + xval;
        }
        __syncthreads();
        // ---- 4. activation: 16 hidden x 4 batches; packed (tag|value) store ----
        if (t < 64){
            float gi = gates_s[((0*16) + ahl)*4 + ab];
            float gf = gates_s[((1*16) + ahl)*4 + ab];
            float gc = gates_s[((2*16) + ahl)*4 + ab];
            float gov = gates_s[((3*16) + ahl)*4 + ab];
            float cp = cst[t];
            float cn = sigf(gf)*cp + sigf(gi)*tanhf(gc);
            float hn = sigf(gov)*tanhf(cn);
            cst[t] = cn;
            unsigned long long pk = ((unsigned long long)(unsigned)(s+1) << 32)
                                  | (unsigned long long)__float_as_uint(hn);
            __hip_atomic_store(&hT[(size_t)(par^1)*(4*HD) + ab*HD + hidx_a], pk,
                               __ATOMIC_RELAXED, __HIP_MEMORY_SCOPE_AGENT);
            hall[(size_t)((b0 + ab)*SL + tx)*HD + hidx_a] = hn;
        }
        // no barrier: next staging only touches h_s (idle since the compute sync),
        // and gates_s/part are rewritten only after two more __syncthreads.
        par ^= 1;
    }
}

// ---------------------------------------------------------------- combine o | bio_emb
__global__ __launch_bounds__(256) void combine_k(const float* __restrict__ hf,
                                                 const float* __restrict__ hb,
                                                 const int* __restrict__ bio_gold,
                                                 const float* __restrict__ bio_emb,
                                                 float* __restrict__ oc)
{
    int idx = blockIdx.x*256 + threadIdx.x;      // float4 index over NTOK*144
    if (idx >= NTOK*144) return;
    int row = idx / 144;
    int c4 = (idx - row*144) * 4;
    float4 v;
    if (c4 < HD){
        float4 a = *(const float4*)(hf + (size_t)row*HD + c4);
        float4 b = *(const float4*)(hb + (size_t)row*HD + c4);
        v = make_float4(0.5f*(a.x+b.x), 0.5f*(a.y+b.y), 0.5f*(a.z+b.z), 0.5f*(a.w+b.w));
    } else {
        int bg = bio_gold[row];
        v = *(const float4*)(bio_emb + bg*BE + (c4 - HD));
    }
    *(float4*)(oc + (size_t)row*OCD + c4) = v;
}

// ---------------------------------------------------------------- CRF NLL
__global__ __launch_bounds__(64) void crf_k(const float* __restrict__ emi,
                                            const int* __restrict__ tags,
                                            const int* __restrict__ tokens,
                                            const float* __restrict__ trans,
                                            const float* __restrict__ startv,
                                            const float* __restrict__ endv,
                                            float* __restrict__ out_crf)
{
    __shared__ float al[16];
    const int b = blockIdx.x, lane = threadIdx.x;
    unsigned long long m0 = __ballot(tokens[b*SL + lane] != 0);
    unsigned long long m1 = __ballot(tokens[b*SL + 64 + lane] != 0);
    const int len = __popcll(m0) + __popcll(m1);
    float npart = 0.f;
    #pragma unroll
    for (int half = 0; half < 2; ++half){
        int tt = lane + half*64;
        if (tt >= 1 && tt < len){
            int tp = tags[b*SL + tt - 1], tc = tags[b*SL + tt];
            npart += trans[tp*NT + tc] + emi[(size_t)(b*SL + tt)*NT + tc];
        }
    }
    #pragma unroll
    for (int off = 32; off > 0; off >>= 1) npart += __shfl_down(npart, off);
    float tr[NT]; float alpha = -1e30f;
    if (lane < NT){
        #pragma unroll
        for (int i = 0; i < NT; ++i) tr[i] = trans[i*NT + lane];
        alpha = startv[lane] + emi[(size_t)(b*SL)*NT + lane];
    }
    for (int tt = 1; tt < SL; ++tt){
        if (lane < NT) al[lane] = alpha;
        __syncthreads();
        if (lane < NT && tt < len){
            float mx = -1e30f;
            #pragma unroll
            for (int i = 0; i < NT; ++i) mx = fmaxf(mx, al[i] + tr[i]);
            float se = 0.f;
            #pragma unroll
            for (int i = 0; i < NT; ++i) se += __expf(al[i] + tr[i] - mx);
            alpha = mx + __logf(se) + emi[(size_t)(b*SL + tt)*NT + lane];
        }
        __syncthreads();
    }
    if (lane < NT) al[lane] = alpha + endv[lane];
    __syncthreads();
    if (lane == 0){
        float mx = -1e30f;
        for (int i = 0; i < NT; ++i) mx = fmaxf(mx, al[i]);
        float se = 0.f;
        for (int i = 0; i < NT; ++i) se += __expf(al[i] - mx);
        float den = mx + __logf(se);
        int t0g = tags[b*SL];
        float num = startv[t0g] + emi[(size_t)(b*SL)*NT + t0g] + npart;
        num += endv[tags[b*SL + len - 1]];
        atomicAdd(out_crf, -(num - den) * (1.0f/16.0f));
    }
}

// ---------------------------------------------------------------- token count
__global__ __launch_bounds__(256) void msum_k(const int* __restrict__ tokens, float* __restrict__ out_m)
{
    __shared__ int rr[4];
    int t = threadIdx.x;
    int cnt = 0;
    for (int i = t; i < NTOK; i += 256) cnt += (tokens[i] != 0) ? 1 : 0;
    #pragma unroll
    for (int off = 32; off > 0; off >>= 1) cnt += __shfl_down(cnt, off);
    if ((t & 63) == 0) rr[t >> 6] = cnt;
    __syncthreads();
    if (t == 0) out_m[0] = (float)(rr[0]+rr[1]+rr[2]+rr[3]);
}

// ---------------------------------------------------------------- fused uv->logits->BCE
__global__ __launch_bounds__(256) void sel_k(const float* __restrict__ U2,
                                             const float* __restrict__ V2,
                                             const float* __restrict__ uvb,
                                             const float* __restrict__ rel_emb,
                                             const int* __restrict__ gold,
                                             const int* __restrict__ tokens,
                                             float* __restrict__ out_sel)
{
    __shared__ float ret_s[RE][52];   // [k][r]
    __shared__ float pt_s[RE][68];    // [k][j]
    __shared__ float vb_s[RE];
    __shared__ float mk_s[64];
    __shared__ float red_s[4];
    const int jt = blockIdx.x, qi = blockIdx.y, b = blockIdx.z;
    const int t = threadIdx.x;
    if (tokens[b*SL + qi] == 0) return;   // pm row entirely zero
    if (t < 32){
        float4 v4 = *(const float4*)(V2 + (size_t)(b*SL + qi)*RE + t*4);
        float4 b4 = *(const float4*)(uvb + t*4);
        vb_s[t*4+0] = v4.x + b4.x; vb_s[t*4+1] = v4.y + b4.y;
        vb_s[t*4+2] = v4.z + b4.z; vb_s[t*4+3] = v4.w + b4.w;
    }
    if (t < 64) mk_s[t] = (tokens[b*SL + jt*64 + t] != 0) ? 1.f : 0.f;
    {
        int r = t & 63;
        for (int q = t >> 6; q < 32; q += 4){
            if (r < NR){
                float4 e4 = *(const float4*)(rel_emb + (size_t)r*RE + q*4);
                ret_s[q*4+0][r] = e4.x; ret_s[q*4+1][r] = e4.y;
                ret_s[q*4+2][r] = e4.z; ret_s[q*4+3][r] = e4.w;
            } else if (r < 64){
                ret_s[q*4+0][r] = 0.f; ret_s[q*4+1][r] = 0.f;
                ret_s[q*4+2][r] = 0.f; ret_s[q*4+3][r] = 0.f;
            }
        }
    }
    __syncthreads();
    {
        int j = t & 63;
        for (int q = t >> 6; q < 32; q += 4){
            float4 u4 = *(const float4*)(U2 + (size_t)(b*SL + jt*64 + j)*RE + q*4);
            pt_s[q*4+0][j] = fmaxf(u4.x + vb_s[q*4+0], 0.f);
            pt_s[q*4+1][j] = fmaxf(u4.y + vb_s[q*4+1], 0.f);
            pt_s[q*4+2][j] = fmaxf(u4.z + vb_s[q*4+2], 0.f);
            pt_s[q*4+3][j] = fmaxf(u4.w + vb_s[q*4+3], 0.f);
        }
    }
    __syncthreads();
    const int mj = (t & 15) * 4;   // j0
    const int nr = (t >> 4) * 4;   // r0
    float accv[4][4];
    #pragma unroll
    for (int i=0;i<4;++i){ accv[i][0]=0.f; accv[i][1]=0.f; accv[i][2]=0.f; accv[i][3]=0.f; }
    #pragma unroll 4
    for (int k = 0; k < RE; ++k){
        float4 aj = *(const float4*)&pt_s[k][mj];
        float4 br = *(const float4*)&ret_s[k][nr];
        float am[4] = {aj.x, aj.y, aj.z, aj.w};
        float bn[4] = {br.x, br.y, br.z, br.w};
        #pragma unroll
        for (int mm = 0; mm < 4; ++mm){
            #pragma unroll
            for (int nn = 0; nn < 4; ++nn)
                accv[mm][nn] += am[mm]*bn[nn];
        }
    }
    float lsum = 0.f;
    #pragma unroll
    for (int nn = 0; nn < 4; ++nn){
        int r = nr + nn;
        if (r < NR){
            const int* gp = gold + (size_t)((b*SL + qi)*NR + r)*SL + jt*64 + mj;
            #pragma unroll
            for (int mm = 0; mm < 4; ++mm){
                float l = accv[mm][nn];
                float g = (float)gp[mm];
                float bce = fmaxf(l, 0.f) - l*g + __logf(1.f + __expf(-fabsf(l)));
                lsum += bce * mk_s[mj + mm];
            }
        }
    }
    #pragma unroll
    for (int off = 32; off > 0; off >>= 1) lsum += __shfl_down(lsum, off);
    if ((t & 63) == 0) red_s[t >> 6] = lsum;
    __syncthreads();
    if (t == 0) atomicAdd(out_sel, red_s[0]+red_s[1]+red_s[2]+red_s[3]);
}

// ---------------------------------------------------------------- finalize
__global__ void finalize_k(const float* __restrict__ accum, float* __restrict__ out)
{
    if (threadIdx.x == 0 && blockIdx.x == 0) out[0] = accum[0] + accum[1] / accum[2];
}

// ---------------------------------------------------------------- launch
extern "C" void kernel_launch(void* const* d_in, const int* in_sizes, int n_in,
                              void* d_out, int out_size, void* d_ws, size_t ws_size,
                              hipStream_t stream)
{
    const int*   tokens    = (const int*)  d_in[0];
    const int*   bio_gold  = (const int*)  d_in[1];
    const int*   sel_gold  = (const int*)  d_in[2];
    // d_in[3] = is_train (unused)
    const float* word_emb  = (const float*)d_in[4];
    const float* rel_emb   = (const float*)d_in[5];
    const float* bio_emb   = (const float*)d_in[6];
    const float* w_ih_f    = (const float*)d_in[7];
    const float* w_hh_f    = (const float*)d_in[8];
    const float* b_ih_f    = (const float*)d_in[9];
    const float* b_hh_f    = (const float*)d_in[10];
    const float* w_ih_b    = (const float*)d_in[11];
    const float* w_hh_b    = (const float*)d_in[12];
    const float* b_ih_b    = (const float*)d_in[13];
    const float* b_hh_b    = (const float*)d_in[14];
    const float* emission_w= (const float*)d_in[15];
    const float* emission_b= (const float*)d_in[16];
    const float* sel_u_w   = (const float*)d_in[17];
    const float* sel_u_b   = (const float*)d_in[18];
    const float* sel_v_w   = (const float*)d_in[19];
    const float* sel_v_b   = (const float*)d_in[20];
    const float* sel_uv_w  = (const float*)d_in[21];
    const float* sel_uv_b  = (const float*)d_in[22];
    const float* crf_trans = (const float*)d_in[23];
    const float* crf_start = (const float*)d_in[24];
    const float* crf_end   = (const float*)d_in[25];
    (void)in_sizes; (void)n_in; (void)out_size; (void)ws_size;

    float* ws     = (float*)d_ws;
    float* emb    = ws;                         // 614400 (dead after xW gemms -> reused below)
    float* xwf    = emb    + (size_t)NTOK*ED;   // 4194304
    float* xwb    = xwf    + (size_t)NTOK*G4;   // 4194304
    float* hf_all = xwb    + (size_t)NTOK*G4;   // 1048576
    float* hb_all = hf_all + (size_t)NTOK*HD;   // 1048576
    float* oc     = hb_all + (size_t)NTOK*HD;   // 1179648
    float* emi    = oc     + (size_t)NTOK*OCD;  // 18432
    float* u_     = emi    + (size_t)NTOK*NT;   // 262144
    float* v_     = u_     + (size_t)NTOK*RE;   // 262144
    float* U2     = v_     + (size_t)NTOK*RE;   // 262144
    float* V2     = U2     + (size_t)NTOK*RE;   // 262144
    float* accum  = V2     + (size_t)NTOK*RE;   // [0]=crf, [1]=sel_sum, [2]=msum, [3]=pad

    // LSTM packed h exchange lives in the emb buffer (dead after the xW GEMMs):
    // 8 teams x 2 parities x 2048 u64 = 256 KB
    unsigned long long* hteam = (unsigned long long*)emb;

    hipMemsetAsync(accum, 0, 4*sizeof(float), stream);

    gather_emb_k<<<(NTOK*ED + 255)/256, 256, 0, stream>>>(tokens, word_emb, emb);

    dim3 gw(NTOK/128, G4/64);
    gemm_k<128><<<gw, 256, 0, stream>>>(emb, ED, w_ih_f, ED, xwf, G4, G4, ED, b_ih_f, b_hh_f, 0);
    gemm_k<128><<<gw, 256, 0, stream>>>(emb, ED, w_ih_b, ED, xwb, G4, G4, ED, b_ih_b, b_hh_b, 0);

    // emb is dead now; zero the packed h buffer (tag 0, value 0.0f == initial h)
    hipMemsetAsync(hteam, 0, (size_t)8*2*(4*HD)*sizeof(unsigned long long), stream);

    {
        const float *p_xwf = xwf, *p_xwb = xwb, *p_whf = w_hh_f, *p_whb = w_hh_b;
        unsigned long long* p_ht = hteam;
        float *p_hf = hf_all, *p_hb = hb_all;
        void* args[7] = {&p_xwf, &p_xwb, &p_whf, &p_whb, &p_ht, &p_hf, &p_hb};
        hipLaunchCooperativeKernel(lstm_k, dim3(256), dim3(256), args, 0u, stream);
    }

    combine_k<<<(NTOK*144 + 255)/256, 256, 0, stream>>>(hf_all, hb_all, bio_gold, bio_emb, oc);

    gemm_k<64><<<dim3(NTOK/64, 1), 256, 0, stream>>>(oc, OCD, emission_w, HD, emi, NT, NT, HD, emission_b, nullptr, 0);
    gemm_k<64><<<dim3(NTOK/64, 2), 256, 0, stream>>>(oc, OCD, sel_u_w, OCD, u_, RE, RE, OCD, sel_u_b, nullptr, 1);
    gemm_k<64><<<dim3(NTOK/64, 2), 256, 0, stream>>>(oc, OCD, sel_v_w, OCD, v_, RE, RE, OCD, sel_v_b, nullptr, 1);
    gemm_k<64><<<dim3(NTOK/64, 2), 256, 0, stream>>>(u_, RE, sel_uv_w,      2*RE, U2, RE, RE, RE, nullptr, nullptr, 0);
    gemm_k<64><<<dim3(NTOK/64, 2), 256, 0, stream>>>(v_, RE, sel_uv_w + RE, 2*RE, V2, RE, RE, RE, nullptr, nullptr, 0);

    crf_k<<<NB, 64, 0, stream>>>(emi, bio_gold, tokens, crf_trans, crf_start, crf_end, accum + 0);
    msum_k<<<1, 256, 0, stream>>>(tokens, accum + 2);
    sel_k<<<dim3(2, SL, NB), 256, 0, stream>>>(U2, V2, sel_uv_b, rel_emb, sel_gold, tokens, accum + 1);

    finalize_k<<<1, 1, 0, stream>>>(accum, (float*)d_out);
}

// Round 5
// 1381.926 us; speedup vs baseline: 1.6524x; 1.6524x over previous
//
#include <hip/hip_runtime.h>
#include <math.h>

// Problem dims
#define NB   16     // batch
#define SL   128    // seq len
#define ED   300    // word emb dim
#define HD   512    // lstm hidden
#define G4   2048   // 4*HD
#define NT   9      // tag count T
#define BE   64     // bio emb dim
#define RE   128    // REL_E
#define NR   50     // R
#define OCD  576    // HD + BE
#define NTOK 2048   // NB*SL

__device__ __forceinline__ float sigf(float x){ return 1.0f/(1.0f + __expf(-x)); }

// ---------------------------------------------------------------- gather emb
__global__ __launch_bounds__(256) void gather_emb_k(const int* __restrict__ tokens,
                                                    const float* __restrict__ word_emb,
                                                    float* __restrict__ emb)
{
    int idx = blockIdx.x*256 + threadIdx.x;
    if (idx < NTOK*ED){
        int row = idx / ED;
        int k = idx - row*ED;
        emb[idx] = word_emb[tokens[row]*ED + k];
    }
}

// ---------------------------------------------------------------- generic fp32 GEMM
// C[m,n] = act( sum_k A[m,k]*B[n,k] + bias1[n] + bias2[n] )
template<int TM>
__global__ __launch_bounds__(256) void gemm_k(const float* __restrict__ A, int lda,
                                              const float* __restrict__ Bm, int ldb,
                                              float* __restrict__ C, int ldc,
                                              int N, int K,
                                              const float* __restrict__ bias1,
                                              const float* __restrict__ bias2,
                                              int do_relu)
{
    constexpr int TR = TM/16;                 // rows per thread (8 or 4)
    __shared__ float As[16][TM+4];            // [k][m]
    __shared__ float Bs[16][68];              // [k][n]
    const int t = threadIdx.x;
    const int m_blk = blockIdx.x * TM;
    const int n_blk = blockIdx.y * 64;
    const int tm = (t >> 4) * TR;
    const int tn = (t & 15) * 4;
    float acc[TR][4];
    #pragma unroll
    for (int i=0;i<TR;++i){ acc[i][0]=0.f; acc[i][1]=0.f; acc[i][2]=0.f; acc[i][3]=0.f; }

    const int kc = (K + 15) >> 4;
    for (int ck = 0; ck < kc; ++ck){
        const int k0 = ck << 4;
        __syncthreads();
        #pragma unroll
        for (int it = 0; it < TM/64; ++it){
            int task = t + it*256;
            int m = task >> 2, q = task & 3;
            int kk = k0 + q*4;
            float4 v = make_float4(0.f,0.f,0.f,0.f);
            const float* ap = A + (size_t)(m_blk + m)*lda + kk;
            if (kk + 3 < K) v = *(const float4*)ap;
            else {
                if (kk   < K) v.x = ap[0];
                if (kk+1 < K) v.y = ap[1];
                if (kk+2 < K) v.z = ap[2];
            }
            As[q*4+0][m] = v.x; As[q*4+1][m] = v.y; As[q*4+2][m] = v.z; As[q*4+3][m] = v.w;
        }
        {
            int n = t >> 2, q = t & 3;
            int kk = k0 + q*4;
            int gn = n_blk + n;
            float4 v = make_float4(0.f,0.f,0.f,0.f);
            if (gn < N){
                const float* bp = Bm + (size_t)gn*ldb + kk;
                if (kk + 3 < K) v = *(const float4*)bp;
                else {
                    if (kk   < K) v.x = bp[0];
                    if (kk+1 < K) v.y = bp[1];
                    if (kk+2 < K) v.z = bp[2];
                }
            }
            Bs[q*4+0][n] = v.x; Bs[q*4+1][n] = v.y; Bs[q*4+2][n] = v.z; Bs[q*4+3][n] = v.w;
        }
        __syncthreads();
        #pragma unroll
        for (int k = 0; k < 16; ++k){
            float4 b4 = *(const float4*)&Bs[k][tn];
            float bn[4] = {b4.x, b4.y, b4.z, b4.w};
            #pragma unroll
            for (int i = 0; i < TR/4; ++i){
                float4 a4 = *(const float4*)&As[k][tm + i*4];
                float am[4] = {a4.x, a4.y, a4.z, a4.w};
                #pragma unroll
                for (int mm = 0; mm < 4; ++mm){
                    #pragma unroll
                    for (int nn = 0; nn < 4; ++nn)
                        acc[i*4+mm][nn] += am[mm]*bn[nn];
                }
            }
        }
    }
    float bv[4];
    #pragma unroll
    for (int nn=0;nn<4;++nn){
        int gn = n_blk + tn + nn;
        float bb = 0.f;
        if (gn < N){
            if (bias1) bb += bias1[gn];
            if (bias2) bb += bias2[gn];
        }
        bv[nn] = bb;
    }
    bool vec = ((ldc & 3) == 0) && (n_blk + tn + 3 < N);
    #pragma unroll
    for (int mm = 0; mm < TR; ++mm){
        int gm = m_blk + tm + mm;
        float r0 = acc[mm][0] + bv[0];
        float r1 = acc[mm][1] + bv[1];
        float r2 = acc[mm][2] + bv[2];
        float r3 = acc[mm][3] + bv[3];
        if (do_relu){ r0=fmaxf(r0,0.f); r1=fmaxf(r1,0.f); r2=fmaxf(r2,0.f); r3=fmaxf(r3,0.f); }
        if (vec){
            *(float4*)(C + (size_t)gm*ldc + n_blk + tn) = make_float4(r0,r1,r2,r3);
        } else {
            int gn = n_blk + tn;
            if (gn   < N) C[(size_t)gm*ldc + gn  ] = r0;
            if (gn+1 < N) C[(size_t)gm*ldc + gn+1] = r1;
            if (gn+2 < N) C[(size_t)gm*ldc + gn+2] = r2;
            if (gn+3 < N) C[(size_t)gm*ldc + gn+3] = r3;
        }
    }
}

// ---------------------------------------------------------------- team-parallel LSTM
// 8 independent teams of 32 wgs; team = (dir = team&1, batches [(team>>1)*4, +4)).
// wg rank owns hidden units [rank*16, +16) (64 gate rows); 128KB weight slice in
// VGPRs (128 VGPR/thread). CRITICAL: both the weight-load loop and the compute
// loop are FULLY unrolled -- R3/R4 used partial unroll, which left w[] with
// loop-variant indices -> scratch allocation (VGPR=36, 1.3GB FETCH of scratch
// re-reads). Full unroll => constant indices => SROA promotes w[] to registers.
// Sync is fused into the data: h exchanged as packed u64 (tag<<32|float_bits)
// relaxed agent atomics; consumers spin until staged entries carry tag s.
__global__ __launch_bounds__(256, 1) void lstm_k(const float* __restrict__ xwf,
                                                 const float* __restrict__ xwb,
                                                 const float* __restrict__ whhf,
                                                 const float* __restrict__ whhb,
                                                 unsigned long long* __restrict__ hteam, // [8][2][2048] u64
                                                 float* __restrict__ hf_all,
                                                 float* __restrict__ hb_all)
{
    __shared__ __align__(16) float h_s[4*HD];      // 8 KB  [b][512]
    __shared__ __align__(16) float part[4*64*4];   // 4 KB  [kq][row][b]
    __shared__ float gates_s[64*4];                // [row][b]
    __shared__ float cst[64];                      // [b*16 + hl]
    const int wg   = blockIdx.x;
    const int team = wg >> 5;
    const int rank = wg & 31;
    const int d    = team & 1;
    const int b0   = (team >> 1) * 4;
    const int t    = threadIdx.x;
    const int kq   = t >> 6;                       // k-quarter (== wave id)
    const int rl   = t & 63;                       // local gate row 0..63
    const int grow = (rl >> 4)*HD + rank*16 + (rl & 15);   // global gate row
    const float* whh = d ? whhb : whhf;
    const float* xw  = d ? xwb  : xwf;
    float* hall      = d ? hb_all : hf_all;
    unsigned long long* hT = hteam + (size_t)team*2*(4*HD);

    // ---- one-time: weight slice into registers (32 float4 = 128 VGPRs) ----
    float4 w[32];
    {
        const float* wp = whh + (size_t)grow*HD + kq*128;
        #pragma unroll
        for (int q = 0; q < 32; ++q) w[q] = *(const float4*)(wp + q*4);
    }
    // reduce mapping: t -> (row, batch)
    const int rrow = t >> 2, rb = t & 3;
    const int growr = (rrow >> 4)*HD + rank*16 + (rrow & 15);
    // activation mapping: t<64 -> (hidden-local, batch)
    const int ahl = t & 15, ab = t >> 4;
    const int hidx_a = rank*16 + ahl;

    if (t < 64) cst[t] = 0.f;
    __syncthreads();

    int par = 0;
    for (int s = 0; s < SL; ++s){
        const int tx = d ? (SL-1 - s) : s;
        // issue the xw read early (independent of staging; hides under the spin)
        const float xval = xw[(size_t)((b0 + rb)*SL + tx)*G4 + growr];
        // ---- 1. stage team h: spin on packed tags (tag == s), 8 u64/thread ----
        {
            const unsigned long long* src = hT + (size_t)par*(4*HD);
            float vals[8];
            unsigned done = 0;
            const unsigned want = (unsigned)s;
            for (;;){
                #pragma unroll
                for (int i = 0; i < 8; ++i){
                    if (!(done & (1u << i))){
                        unsigned long long v = __hip_atomic_load(&src[t + i*256],
                                                  __ATOMIC_RELAXED, __HIP_MEMORY_SCOPE_AGENT);
                        if ((unsigned)(v >> 32) == want){
                            vals[i] = __uint_as_float((unsigned)v);
                            done |= (1u << i);
                        }
                    }
                }
                if (done == 0xFFu) break;
                __builtin_amdgcn_s_sleep(1);
            }
            #pragma unroll
            for (int i = 0; i < 8; ++i) h_s[t + i*256] = vals[i];
        }
        __syncthreads();
        // ---- 2. partial dots: row rl, k-quarter kq, all 4 batches (FULL unroll) ----
        {
            float a0=0.f, a1=0.f, a2=0.f, a3=0.f;
            const float* hb_ = h_s + kq*128;       // wave-uniform base -> LDS broadcast
            #pragma unroll
            for (int q = 0; q < 32; ++q){
                float4 wq = w[q];
                float4 h0 = *(const float4*)(hb_ + 0*HD + q*4);
                float4 h1 = *(const float4*)(hb_ + 1*HD + q*4);
                float4 h2 = *(const float4*)(hb_ + 2*HD + q*4);
                float4 h3 = *(const float4*)(hb_ + 3*HD + q*4);
                a0 += wq.x*h0.x + wq.y*h0.y + wq.z*h0.z + wq.w*h0.w;
                a1 += wq.x*h1.x + wq.y*h1.y + wq.z*h1.z + wq.w*h1.w;
                a2 += wq.x*h2.x + wq.y*h2.y + wq.z*h2.z + wq.w*h2.w;
                a3 += wq.x*h3.x + wq.y*h3.y + wq.z*h3.z + wq.w*h3.w;
            }
            *(float4*)&part[(kq*64 + rl)*4] = make_float4(a0,a1,a2,a3);
        }
        __syncthreads();
        // ---- 3. reduce k-quarters + add xW (biases folded into xW) ----
        {
            float gsum = part[(0*64 + rrow)*4 + rb] + part[(1*64 + rrow)*4 + rb]
                       + part[(2*64 + rrow)*4 + rb] + part[(3*64 + rrow)*4 + rb];
            gates_s[rrow*4 + rb] = gsum + xval;
        }
        __syncthreads();
        // ---- 4. activation: 16 hidden x 4 batches; packed (tag|value) store ----
        if (t < 64){
            float gi = gates_s[((0*16) + ahl)*4 + ab];
            float gf = gates_s[((1*16) + ahl)*4 + ab];
            float gc = gates_s[((2*16) + ahl)*4 + ab];
            float gov = gates_s[((3*16) + ahl)*4 + ab];
            float cp = cst[t];
            float cn = sigf(gf)*cp + sigf(gi)*tanhf(gc);
            float hn = sigf(gov)*tanhf(cn);
            cst[t] = cn;
            unsigned long long pk = ((unsigned long long)(unsigned)(s+1) << 32)
                                  | (unsigned long long)__float_as_uint(hn);
            __hip_atomic_store(&hT[(size_t)(par^1)*(4*HD) + ab*HD + hidx_a], pk,
                               __ATOMIC_RELAXED, __HIP_MEMORY_SCOPE_AGENT);
            hall[(size_t)((b0 + ab)*SL + tx)*HD + hidx_a] = hn;
        }
        // no barrier needed: h_s is only rewritten in next staging, which all
        // threads reach only after the phase-2->3 barrier fenced their h_s reads.
        par ^= 1;
    }
}

// ---------------------------------------------------------------- combine o | bio_emb
__global__ __launch_bounds__(256) void combine_k(const float* __restrict__ hf,
                                                 const float* __restrict__ hb,
                                                 const int* __restrict__ bio_gold,
                                                 const float* __restrict__ bio_emb,
                                                 float* __restrict__ oc)
{
    int idx = blockIdx.x*256 + threadIdx.x;      // float4 index over NTOK*144
    if (idx >= NTOK*144) return;
    int row = idx / 144;
    int c4 = (idx - row*144) * 4;
    float4 v;
    if (c4 < HD){
        float4 a = *(const float4*)(hf + (size_t)row*HD + c4);
        float4 b = *(const float4*)(hb + (size_t)row*HD + c4);
        v = make_float4(0.5f*(a.x+b.x), 0.5f*(a.y+b.y), 0.5f*(a.z+b.z), 0.5f*(a.w+b.w));
    } else {
        int bg = bio_gold[row];
        v = *(const float4*)(bio_emb + bg*BE + (c4 - HD));
    }
    *(float4*)(oc + (size_t)row*OCD + c4) = v;
}

// ---------------------------------------------------------------- CRF NLL
__global__ __launch_bounds__(64) void crf_k(const float* __restrict__ emi,
                                            const int* __restrict__ tags,
                                            const int* __restrict__ tokens,
                                            const float* __restrict__ trans,
                                            const float* __restrict__ startv,
                                            const float* __restrict__ endv,
                                            float* __restrict__ out_crf)
{
    __shared__ float al[16];
    const int b = blockIdx.x, lane = threadIdx.x;
    unsigned long long m0 = __ballot(tokens[b*SL + lane] != 0);
    unsigned long long m1 = __ballot(tokens[b*SL + 64 + lane] != 0);
    const int len = __popcll(m0) + __popcll(m1);
    float npart = 0.f;
    #pragma unroll
    for (int half = 0; half < 2; ++half){
        int tt = lane + half*64;
        if (tt >= 1 && tt < len){
            int tp = tags[b*SL + tt - 1], tc = tags[b*SL + tt];
            npart += trans[tp*NT + tc] + emi[(size_t)(b*SL + tt)*NT + tc];
        }
    }
    #pragma unroll
    for (int off = 32; off > 0; off >>= 1) npart += __shfl_down(npart, off);
    float tr[NT]; float alpha = -1e30f;
    if (lane < NT){
        #pragma unroll
        for (int i = 0; i < NT; ++i) tr[i] = trans[i*NT + lane];
        alpha = startv[lane] + emi[(size_t)(b*SL)*NT + lane];
    }
    for (int tt = 1; tt < SL; ++tt){
        if (lane < NT) al[lane] = alpha;
        __syncthreads();
        if (lane < NT && tt < len){
            float mx = -1e30f;
            #pragma unroll
            for (int i = 0; i < NT; ++i) mx = fmaxf(mx, al[i] + tr[i]);
            float se = 0.f;
            #pragma unroll
            for (int i = 0; i < NT; ++i) se += __expf(al[i] + tr[i] - mx);
            alpha = mx + __logf(se) + emi[(size_t)(b*SL + tt)*NT + lane];
        }
        __syncthreads();
    }
    if (lane < NT) al[lane] = alpha + endv[lane];
    __syncthreads();
    if (lane == 0){
        float mx = -1e30f;
        for (int i = 0; i < NT; ++i) mx = fmaxf(mx, al[i]);
        float se = 0.f;
        for (int i = 0; i < NT; ++i) se += __expf(al[i] - mx);
        float den = mx + __logf(se);
        int t0g = tags[b*SL];
        float num = startv[t0g] + emi[(size_t)(b*SL)*NT + t0g] + npart;
        num += endv[tags[b*SL + len - 1]];
        atomicAdd(out_crf, -(num - den) * (1.0f/16.0f));
    }
}

// ---------------------------------------------------------------- token count
__global__ __launch_bounds__(256) void msum_k(const int* __restrict__ tokens, float* __restrict__ out_m)
{
    __shared__ int rr[4];
    int t = threadIdx.x;
    int cnt = 0;
    for (int i = t; i < NTOK; i += 256) cnt += (tokens[i] != 0) ? 1 : 0;
    #pragma unroll
    for (int off = 32; off > 0; off >>= 1) cnt += __shfl_down(cnt, off);
    if ((t & 63) == 0) rr[t >> 6] = cnt;
    __syncthreads();
    if (t == 0) out_m[0] = (float)(rr[0]+rr[1]+rr[2]+rr[3]);
}

// ---------------------------------------------------------------- fused uv->logits->BCE
__global__ __launch_bounds__(256) void sel_k(const float* __restrict__ U2,
                                             const float* __restrict__ V2,
                                             const float* __restrict__ uvb,
                                             const float* __restrict__ rel_emb,
                                             const int* __restrict__ gold,
                                             const int* __restrict__ tokens,
                                             float* __restrict__ out_sel)
{
    __shared__ float ret_s[RE][52];   // [k][r]
    __shared__ float pt_s[RE][68];    // [k][j]
    __shared__ float vb_s[RE];
    __shared__ float mk_s[64];
    __shared__ float red_s[4];
    const int jt = blockIdx.x, qi = blockIdx.y, b = blockIdx.z;
    const int t = threadIdx.x;
    if (tokens[b*SL + qi] == 0) return;   // pm row entirely zero
    if (t < 32){
        float4 v4 = *(const float4*)(V2 + (size_t)(b*SL + qi)*RE + t*4);
        float4 b4 = *(const float4*)(uvb + t*4);
        vb_s[t*4+0] = v4.x + b4.x; vb_s[t*4+1] = v4.y + b4.y;
        vb_s[t*4+2] = v4.z + b4.z; vb_s[t*4+3] = v4.w + b4.w;
    }
    if (t < 64) mk_s[t] = (tokens[b*SL + jt*64 + t] != 0) ? 1.f : 0.f;
    {
        int r = t & 63;
        for (int q = t >> 6; q < 32; q += 4){
            if (r < NR){
                float4 e4 = *(const float4*)(rel_emb + (size_t)r*RE + q*4);
                ret_s[q*4+0][r] = e4.x; ret_s[q*4+1][r] = e4.y;
                ret_s[q*4+2][r] = e4.z; ret_s[q*4+3][r] = e4.w;
            } else if (r < 64){
                ret_s[q*4+0][r] = 0.f; ret_s[q*4+1][r] = 0.f;
                ret_s[q*4+2][r] = 0.f; ret_s[q*4+3][r] = 0.f;
            }
        }
    }
    __syncthreads();
    {
        int j = t & 63;
        for (int q = t >> 6; q < 32; q += 4){
            float4 u4 = *(const float4*)(U2 + (size_t)(b*SL + jt*64 + j)*RE + q*4);
            pt_s[q*4+0][j] = fmaxf(u4.x + vb_s[q*4+0], 0.f);
            pt_s[q*4+1][j] = fmaxf(u4.y + vb_s[q*4+1], 0.f);
            pt_s[q*4+2][j] = fmaxf(u4.z + vb_s[q*4+2], 0.f);
            pt_s[q*4+3][j] = fmaxf(u4.w + vb_s[q*4+3], 0.f);
        }
    }
    __syncthreads();
    const int mj = (t & 15) * 4;   // j0
    const int nr = (t >> 4) * 4;   // r0
    float accv[4][4];
    #pragma unroll
    for (int i=0;i<4;++i){ accv[i][0]=0.f; accv[i][1]=0.f; accv[i][2]=0.f; accv[i][3]=0.f; }
    #pragma unroll 4
    for (int k = 0; k < RE; ++k){
        float4 aj = *(const float4*)&pt_s[k][mj];
        float4 br = *(const float4*)&ret_s[k][nr];
        float am[4] = {aj.x, aj.y, aj.z, aj.w};
        float bn[4] = {br.x, br.y, br.z, br.w};
        #pragma unroll
        for (int mm = 0; mm < 4; ++mm){
            #pragma unroll
            for (int nn = 0; nn < 4; ++nn)
                accv[mm][nn] += am[mm]*bn[nn];
        }
    }
    float lsum = 0.f;
    #pragma unroll
    for (int nn = 0; nn < 4; ++nn){
        int r = nr + nn;
        if (r < NR){
            const int* gp = gold + (size_t)((b*SL + qi)*NR + r)*SL + jt*64 + mj;
            #pragma unroll
            for (int mm = 0; mm < 4; ++mm){
                float l = accv[mm][nn];
                float g = (float)gp[mm];
                float bce = fmaxf(l, 0.f) - l*g + __logf(1.f + __expf(-fabsf(l)));
                lsum += bce * mk_s[mj + mm];
            }
        }
    }
    #pragma unroll
    for (int off = 32; off > 0; off >>= 1) lsum += __shfl_down(lsum, off);
    if ((t & 63) == 0) red_s[t >> 6] = lsum;
    __syncthreads();
    if (t == 0) atomicAdd(out_sel, red_s[0]+red_s[1]+red_s[2]+red_s[3]);
}

// ---------------------------------------------------------------- finalize
__global__ void finalize_k(const float* __restrict__ accum, float* __restrict__ out)
{
    if (threadIdx.x == 0 && blockIdx.x == 0) out[0] = accum[0] + accum[1] / accum[2];
}

// ---------------------------------------------------------------- launch
extern "C" void kernel_launch(void* const* d_in, const int* in_sizes, int n_in,
                              void* d_out, int out_size, void* d_ws, size_t ws_size,
                              hipStream_t stream)
{
    const int*   tokens    = (const int*)  d_in[0];
    const int*   bio_gold  = (const int*)  d_in[1];
    const int*   sel_gold  = (const int*)  d_in[2];
    // d_in[3] = is_train (unused)
    const float* word_emb  = (const float*)d_in[4];
    const float* rel_emb   = (const float*)d_in[5];
    const float* bio_emb   = (const float*)d_in[6];
    const float* w_ih_f    = (const float*)d_in[7];
    const float* w_hh_f    = (const float*)d_in[8];
    const float* b_ih_f    = (const float*)d_in[9];
    const float* b_hh_f    = (const float*)d_in[10];
    const float* w_ih_b    = (const float*)d_in[11];
    const float* w_hh_b    = (const float*)d_in[12];
    const float* b_ih_b    = (const float*)d_in[13];
    const float* b_hh_b    = (const float*)d_in[14];
    const float* emission_w= (const float*)d_in[15];
    const float* emission_b= (const float*)d_in[16];
    const float* sel_u_w   = (const float*)d_in[17];
    const float* sel_u_b   = (const float*)d_in[18];
    const float* sel_v_w   = (const float*)d_in[19];
    const float* sel_v_b   = (const float*)d_in[20];
    const float* sel_uv_w  = (const float*)d_in[21];
    const float* sel_uv_b  = (const float*)d_in[22];
    const float* crf_trans = (const float*)d_in[23];
    const float* crf_start = (const float*)d_in[24];
    const float* crf_end   = (const float*)d_in[25];
    (void)in_sizes; (void)n_in; (void)out_size; (void)ws_size;

    float* ws     = (float*)d_ws;
    float* emb    = ws;                         // 614400 (dead after xW gemms -> reused below)
    float* xwf    = emb    + (size_t)NTOK*ED;   // 4194304
    float* xwb    = xwf    + (size_t)NTOK*G4;   // 4194304
    float* hf_all = xwb    + (size_t)NTOK*G4;   // 1048576
    float* hb_all = hf_all + (size_t)NTOK*HD;   // 1048576
    float* oc     = hb_all + (size_t)NTOK*HD;   // 1179648
    float* emi    = oc     + (size_t)NTOK*OCD;  // 18432
    float* u_     = emi    + (size_t)NTOK*NT;   // 262144
    float* v_     = u_     + (size_t)NTOK*RE;   // 262144
    float* U2     = v_     + (size_t)NTOK*RE;   // 262144
    float* V2     = U2     + (size_t)NTOK*RE;   // 262144
    float* accum  = V2     + (size_t)NTOK*RE;   // [0]=crf, [1]=sel_sum, [2]=msum, [3]=pad

    // LSTM packed h exchange lives in the emb buffer (dead after the xW GEMMs):
    // 8 teams x 2 parities x 2048 u64 = 256 KB
    unsigned long long* hteam = (unsigned long long*)emb;

    hipMemsetAsync(accum, 0, 4*sizeof(float), stream);

    gather_emb_k<<<(NTOK*ED + 255)/256, 256, 0, stream>>>(tokens, word_emb, emb);

    dim3 gw(NTOK/128, G4/64);
    gemm_k<128><<<gw, 256, 0, stream>>>(emb, ED, w_ih_f, ED, xwf, G4, G4, ED, b_ih_f, b_hh_f, 0);
    gemm_k<128><<<gw, 256, 0, stream>>>(emb, ED, w_ih_b, ED, xwb, G4, G4, ED, b_ih_b, b_hh_b, 0);

    // emb is dead now; zero the packed h buffer (tag 0, value 0.0f == initial h)
    hipMemsetAsync(hteam, 0, (size_t)8*2*(4*HD)*sizeof(unsigned long long), stream);

    {
        const float *p_xwf = xwf, *p_xwb = xwb, *p_whf = w_hh_f, *p_whb = w_hh_b;
        unsigned long long* p_ht = hteam;
        float *p_hf = hf_all, *p_hb = hb_all;
        void* args[7] = {&p_xwf, &p_xwb, &p_whf, &p_whb, &p_ht, &p_hf, &p_hb};
        hipLaunchCooperativeKernel(lstm_k, dim3(256), dim3(256), args, 0u, stream);
    }

    combine_k<<<(NTOK*144 + 255)/256, 256, 0, stream>>>(hf_all, hb_all, bio_gold, bio_emb, oc);

    gemm_k<64><<<dim3(NTOK/64, 1), 256, 0, stream>>>(oc, OCD, emission_w, HD, emi, NT, NT, HD, emission_b, nullptr, 0);
    gemm_k<64><<<dim3(NTOK/64, 2), 256, 0, stream>>>(oc, OCD, sel_u_w, OCD, u_, RE, RE, OCD, sel_u_b, nullptr, 1);
    gemm_k<64><<<dim3(NTOK/64, 2), 256, 0, stream>>>(oc, OCD, sel_v_w, OCD, v_, RE, RE, OCD, sel_v_b, nullptr, 1);
    gemm_k<64><<<dim3(NTOK/64, 2), 256, 0, stream>>>(u_, RE, sel_uv_w,      2*RE, U2, RE, RE, RE, nullptr, nullptr, 0);
    gemm_k<64><<<dim3(NTOK/64, 2), 256, 0, stream>>>(v_, RE, sel_uv_w + RE, 2*RE, V2, RE, RE, RE, nullptr, nullptr, 0);

    crf_k<<<NB, 64, 0, stream>>>(emi, bio_gold, tokens, crf_trans, crf_start, crf_end, accum + 0);
    msum_k<<<1, 256, 0, stream>>>(tokens, accum + 2);
    sel_k<<<dim3(2, SL, NB), 256, 0, stream>>>(U2, V2, sel_uv_b, rel_emb, sel_gold, tokens, accum + 1);

    finalize_k<<<1, 1, 0, stream>>>(accum, (float*)d_out);
}

// Round 6
// 1187.541 us; speedup vs baseline: 1.9228x; 1.1637x over previous
//
#include <hip/hip_runtime.h>
#include <math.h>

// Problem dims
#define NB   16     // batch
#define SL   128    // seq len
#define ED   300    // word emb dim
#define HD   512    // lstm hidden
#define G4   2048   // 4*HD
#define NT   9      // tag count T
#define BE   64     // bio emb dim
#define RE   128    // REL_E
#define NR   50     // R
#define OCD  576    // HD + BE
#define NTOK 2048   // NB*SL

__device__ __forceinline__ float sigf(float x){ return 1.0f/(1.0f + __expf(-x)); }

// ---------------------------------------------------------------- gather emb
__global__ __launch_bounds__(256) void gather_emb_k(const int* __restrict__ tokens,
                                                    const float* __restrict__ word_emb,
                                                    float* __restrict__ emb)
{
    int idx = blockIdx.x*256 + threadIdx.x;
    if (idx < NTOK*ED){
        int row = idx / ED;
        int k = idx - row*ED;
        emb[idx] = word_emb[tokens[row]*ED + k];
    }
}

// ---------------------------------------------------------------- generic fp32 GEMM body
// C[m,n] = act( sum_k A[m,k]*B[n,k] + bias1[n] + bias2[n] )
template<int TM>
__device__ __forceinline__ void gemm_body(const float* __restrict__ A, int lda,
                                          const float* __restrict__ Bm, int ldb,
                                          float* __restrict__ C, int ldc,
                                          int N, int K,
                                          const float* __restrict__ bias1,
                                          const float* __restrict__ bias2,
                                          int do_relu, int m_blk, int n_blk)
{
    constexpr int TR = TM/16;                 // rows per thread (8 or 4)
    __shared__ float As[16][TM+4];            // [k][m]
    __shared__ float Bs[16][68];              // [k][n]
    const int t = threadIdx.x;
    const int tm = (t >> 4) * TR;
    const int tn = (t & 15) * 4;
    float acc[TR][4];
    #pragma unroll
    for (int i=0;i<TR;++i){ acc[i][0]=0.f; acc[i][1]=0.f; acc[i][2]=0.f; acc[i][3]=0.f; }

    const int kc = (K + 15) >> 4;
    for (int ck = 0; ck < kc; ++ck){
        const int k0 = ck << 4;
        __syncthreads();
        #pragma unroll
        for (int it = 0; it < TM/64; ++it){
            int task = t + it*256;
            int m = task >> 2, q = task & 3;
            int kk = k0 + q*4;
            float4 v = make_float4(0.f,0.f,0.f,0.f);
            const float* ap = A + (size_t)(m_blk + m)*lda + kk;
            if (kk + 3 < K) v = *(const float4*)ap;
            else {
                if (kk   < K) v.x = ap[0];
                if (kk+1 < K) v.y = ap[1];
                if (kk+2 < K) v.z = ap[2];
            }
            As[q*4+0][m] = v.x; As[q*4+1][m] = v.y; As[q*4+2][m] = v.z; As[q*4+3][m] = v.w;
        }
        {
            int n = t >> 2, q = t & 3;
            int kk = k0 + q*4;
            int gn = n_blk + n;
            float4 v = make_float4(0.f,0.f,0.f,0.f);
            if (gn < N){
                const float* bp = Bm + (size_t)gn*ldb + kk;
                if (kk + 3 < K) v = *(const float4*)bp;
                else {
                    if (kk   < K) v.x = bp[0];
                    if (kk+1 < K) v.y = bp[1];
                    if (kk+2 < K) v.z = bp[2];
                }
            }
            Bs[q*4+0][n] = v.x; Bs[q*4+1][n] = v.y; Bs[q*4+2][n] = v.z; Bs[q*4+3][n] = v.w;
        }
        __syncthreads();
        #pragma unroll
        for (int k = 0; k < 16; ++k){
            float4 b4 = *(const float4*)&Bs[k][tn];
            float bn[4] = {b4.x, b4.y, b4.z, b4.w};
            #pragma unroll
            for (int i = 0; i < TR/4; ++i){
                float4 a4 = *(const float4*)&As[k][tm + i*4];
                float am[4] = {a4.x, a4.y, a4.z, a4.w};
                #pragma unroll
                for (int mm = 0; mm < 4; ++mm){
                    #pragma unroll
                    for (int nn = 0; nn < 4; ++nn)
                        acc[i*4+mm][nn] += am[mm]*bn[nn];
                }
            }
        }
    }
    float bv[4];
    #pragma unroll
    for (int nn=0;nn<4;++nn){
        int gn = n_blk + tn + nn;
        float bb = 0.f;
        if (gn < N){
            if (bias1) bb += bias1[gn];
            if (bias2) bb += bias2[gn];
        }
        bv[nn] = bb;
    }
    bool vec = ((ldc & 3) == 0) && (n_blk + tn + 3 < N);
    #pragma unroll
    for (int mm = 0; mm < TR; ++mm){
        int gm = m_blk + tm + mm;
        float r0 = acc[mm][0] + bv[0];
        float r1 = acc[mm][1] + bv[1];
        float r2 = acc[mm][2] + bv[2];
        float r3 = acc[mm][3] + bv[3];
        if (do_relu){ r0=fmaxf(r0,0.f); r1=fmaxf(r1,0.f); r2=fmaxf(r2,0.f); r3=fmaxf(r3,0.f); }
        if (vec){
            *(float4*)(C + (size_t)gm*ldc + n_blk + tn) = make_float4(r0,r1,r2,r3);
        } else {
            int gn = n_blk + tn;
            if (gn   < N) C[(size_t)gm*ldc + gn  ] = r0;
            if (gn+1 < N) C[(size_t)gm*ldc + gn+1] = r1;
            if (gn+2 < N) C[(size_t)gm*ldc + gn+2] = r2;
            if (gn+3 < N) C[(size_t)gm*ldc + gn+3] = r3;
        }
    }
}

template<int TM>
__global__ __launch_bounds__(256) void gemm_k(const float* __restrict__ A, int lda,
                                              const float* __restrict__ Bm, int ldb,
                                              float* __restrict__ C, int ldc,
                                              int N, int K,
                                              const float* __restrict__ bias1,
                                              const float* __restrict__ bias2,
                                              int do_relu)
{
    gemm_body<TM>(A, lda, Bm, ldb, C, ldc, N, K, bias1, bias2, do_relu,
                  blockIdx.x * TM, blockIdx.y * 64);
}

// dual: blockIdx.z selects (A,B,C,bias) set — merges two same-shape GEMMs into one launch
template<int TM>
__global__ __launch_bounds__(256) void gemm_dual_k(const float* __restrict__ A0, const float* __restrict__ A1, int lda,
                                                   const float* __restrict__ B0, const float* __restrict__ B1, int ldb,
                                                   float* __restrict__ C0, float* __restrict__ C1, int ldc,
                                                   int N, int K,
                                                   const float* __restrict__ bias0, const float* __restrict__ bias1,
                                                   int do_relu)
{
    const int z = blockIdx.z;
    gemm_body<TM>(z ? A1 : A0, lda, z ? B1 : B0, ldb, z ? C1 : C0, ldc, N, K,
                  z ? bias1 : bias0, nullptr, do_relu, blockIdx.x * TM, blockIdx.y * 64);
}

// ---------------------------------------------------------------- team-parallel LSTM
// 8 teams of 32 wgs; team = (dir = team&1, batches [(team>>1)*4, +4)). wg rank owns
// hidden [rank*16,+16) (64 gate rows); weights in VGPRs (fully unrolled indices).
// R6 remap: thread = (row-group rg = t&31 -> 2 rows, k-chunk kc = t>>5 -> 64 k).
// Each h LDS read now feeds 2 rows (FMA:LDS 8:1, half the ds_read instrs of R5),
// and wave w stages ONLY its own k-span [w*128,+128) into a wave-private LDS
// region -> no stage barrier; per-wave independent spin absorbs producer skew.
// h exchange: packed u64 (tag<<32|float_bits) relaxed agent atomics (unchanged).
__global__ __launch_bounds__(256, 1) void lstm_k(const float* __restrict__ xwf,
                                                 const float* __restrict__ xwb,
                                                 const float* __restrict__ whhf,
                                                 const float* __restrict__ whhb,
                                                 unsigned long long* __restrict__ hteam, // [8][2][2048] u64
                                                 float* __restrict__ hf_all,
                                                 float* __restrict__ hb_all)
{
    __shared__ __align__(16) float h_s[4*HD];      // 8 KB  [b][512]
    __shared__ __align__(16) float part[8*256];    // 8 KB  [kc][row*4+b]
    __shared__ float gates_s[256];                 // [row*4 + b]
    __shared__ float cst[64];                      // [b*16 + hl]
    const int wg   = blockIdx.x;
    const int team = wg >> 5;
    const int rank = wg & 31;
    const int d    = team & 1;
    const int b0   = (team >> 1) * 4;
    const int t    = threadIdx.x;
    const int wv   = t >> 6;                       // wave 0..3
    const int lane = t & 63;
    const int rg   = t & 31;                       // row-group -> rows rg*2, rg*2+1
    const int kc   = t >> 5;                       // k-chunk 0..7 (64 k each)
    const int lr0  = rg*2, lr1 = rg*2 + 1;         // local gate rows
    const int grow0 = (lr0 >> 4)*HD + rank*16 + (lr0 & 15);
    const int grow1 = (lr1 >> 4)*HD + rank*16 + (lr1 & 15);
    const float* whh = d ? whhb : whhf;
    const float* xw  = d ? xwb  : xwf;
    float* hall      = d ? hb_all : hf_all;
    unsigned long long* hT = hteam + (size_t)team*2*(4*HD);

    // ---- one-time: 2 rows x 64 k weights into registers (32 float4 = 128 VGPRs) ----
    float4 w0[16], w1[16];
    {
        const float* wp0 = whh + (size_t)grow0*HD + kc*64;
        const float* wp1 = whh + (size_t)grow1*HD + kc*64;
        #pragma unroll
        for (int q = 0; q < 16; ++q){ w0[q] = *(const float4*)(wp0 + q*4);
                                      w1[q] = *(const float4*)(wp1 + q*4); }
    }
    // reduce mapping: t -> (row rrow, batch rb); gates_s[t] corresponds to it
    const int rrow = t >> 2, rb = t & 3;
    const int growr = (rrow >> 4)*HD + rank*16 + (rrow & 15);
    // activation mapping: t<64 -> (hid-local ahl, batch ab)
    const int ahl = t & 15, ab = t >> 4;
    const int hidx_a = rank*16 + ahl;
    // staging offsets: wave wv stages k-span [wv*128, +128) for all 4 batches
    // idx(i) = (i>>1)*512 + wv*128 + (i&1)*64 + lane
    const int sb = wv*128 + lane;

    if (t < 64) cst[t] = 0.f;
    __syncthreads();

    int par = 0;
    for (int s = 0; s < SL; ++s){
        const int tx = d ? (SL-1 - s) : s;
        // xw value for the reduce phase (issued early, hides under the spin)
        const float xval = xw[(size_t)((b0 + rb)*SL + tx)*G4 + growr];
        // ---- 1. per-wave staging: spin on packed tags (tag == s), 8 u64/thread ----
        {
            const unsigned long long* src = hT + (size_t)par*(4*HD);
            float vals[8];
            unsigned done = 0;
            const unsigned want = (unsigned)s;
            for (;;){
                #pragma unroll
                for (int i = 0; i < 8; ++i){
                    if (!(done & (1u << i))){
                        unsigned long long v = __hip_atomic_load(&src[(i>>1)*512 + (i&1)*64 + sb],
                                                  __ATOMIC_RELAXED, __HIP_MEMORY_SCOPE_AGENT);
                        if ((unsigned)(v >> 32) == want){
                            vals[i] = __uint_as_float((unsigned)v);
                            done |= (1u << i);
                        }
                    }
                }
                if (done == 0xFFu) break;
                __builtin_amdgcn_s_sleep(1);
            }
            #pragma unroll
            for (int i = 0; i < 8; ++i)
                h_s[(i>>1)*HD + (i&1)*64 + sb] = vals[i];
        }
        // NO barrier: each wave reads only the h_s region it just wrote.
        // ---- 2. partial dots: 2 rows x 4 batches x 64 k ----
        {
            float a0[4] = {0.f,0.f,0.f,0.f};
            float a1[4] = {0.f,0.f,0.f,0.f};
            #pragma unroll
            for (int q = 0; q < 16; ++q){
                float4 wa = w0[q], wb = w1[q];
                #pragma unroll
                for (int b = 0; b < 4; ++b){
                    float4 h4 = *(const float4*)(h_s + b*HD + kc*64 + q*4);
                    a0[b] += wa.x*h4.x + wa.y*h4.y + wa.z*h4.z + wa.w*h4.w;
                    a1[b] += wb.x*h4.x + wb.y*h4.y + wb.z*h4.z + wb.w*h4.w;
                }
            }
            *(float4*)&part[kc*256 + lr0*4] = make_float4(a0[0],a0[1],a0[2],a0[3]);
            *(float4*)&part[kc*256 + lr1*4] = make_float4(a1[0],a1[1],a1[2],a1[3]);
        }
        __syncthreads();
        // ---- 3. reduce 8 k-chunks + add xW (biases folded into xW) ----
        {
            float gsum = 0.f;
            #pragma unroll
            for (int c = 0; c < 8; ++c) gsum += part[c*256 + t];
            gates_s[t] = gsum + xval;
        }
        __syncthreads();
        // ---- 4. activation: 16 hidden x 4 batches; packed (tag|value) store ----
        if (t < 64){
            float gi = gates_s[((0*16) + ahl)*4 + ab];
            float gf = gates_s[((1*16) + ahl)*4 + ab];
            float gc = gates_s[((2*16) + ahl)*4 + ab];
            float gov = gates_s[((3*16) + ahl)*4 + ab];
            float cp = cst[t];
            float cn = sigf(gf)*cp + sigf(gi)*tanhf(gc);
            float hn = sigf(gov)*tanhf(cn);
            cst[t] = cn;
            unsigned long long pk = ((unsigned long long)(unsigned)(s+1) << 32)
                                  | (unsigned long long)__float_as_uint(hn);
            __hip_atomic_store(&hT[(size_t)(par^1)*(4*HD) + ab*HD + hidx_a], pk,
                               __ATOMIC_RELAXED, __HIP_MEMORY_SCOPE_AGENT);
            hall[(size_t)((b0 + ab)*SL + tx)*HD + hidx_a] = hn;
        }
        // safe without a trailing barrier: next part-write happens only after this
        // step's post-reduce barrier; gates_s rewrite only after next sync1.
        par ^= 1;
    }
}

// ---------------------------------------------------------------- combine o | bio_emb
__global__ __launch_bounds__(256) void combine_k(const float* __restrict__ hf,
                                                 const float* __restrict__ hb,
                                                 const int* __restrict__ bio_gold,
                                                 const float* __restrict__ bio_emb,
                                                 float* __restrict__ oc)
{
    int idx = blockIdx.x*256 + threadIdx.x;      // float4 index over NTOK*144
    if (idx >= NTOK*144) return;
    int row = idx / 144;
    int c4 = (idx - row*144) * 4;
    float4 v;
    if (c4 < HD){
        float4 a = *(const float4*)(hf + (size_t)row*HD + c4);
        float4 b = *(const float4*)(hb + (size_t)row*HD + c4);
        v = make_float4(0.5f*(a.x+b.x), 0.5f*(a.y+b.y), 0.5f*(a.z+b.z), 0.5f*(a.w+b.w));
    } else {
        int bg = bio_gold[row];
        v = *(const float4*)(bio_emb + bg*BE + (c4 - HD));
    }
    *(float4*)(oc + (size_t)row*OCD + c4) = v;
}

// ---------------------------------------------------------------- CRF NLL
__global__ __launch_bounds__(64) void crf_k(const float* __restrict__ emi,
                                            const int* __restrict__ tags,
                                            const int* __restrict__ tokens,
                                            const float* __restrict__ trans,
                                            const float* __restrict__ startv,
                                            const float* __restrict__ endv,
                                            float* __restrict__ out_crf)
{
    __shared__ float al[16];
    const int b = blockIdx.x, lane = threadIdx.x;
    unsigned long long m0 = __ballot(tokens[b*SL + lane] != 0);
    unsigned long long m1 = __ballot(tokens[b*SL + 64 + lane] != 0);
    const int len = __popcll(m0) + __popcll(m1);
    float npart = 0.f;
    #pragma unroll
    for (int half = 0; half < 2; ++half){
        int tt = lane + half*64;
        if (tt >= 1 && tt < len){
            int tp = tags[b*SL + tt - 1], tc = tags[b*SL + tt];
            npart += trans[tp*NT + tc] + emi[(size_t)(b*SL + tt)*NT + tc];
        }
    }
    #pragma unroll
    for (int off = 32; off > 0; off >>= 1) npart += __shfl_down(npart, off);
    float tr[NT]; float alpha = -1e30f;
    if (lane < NT){
        #pragma unroll
        for (int i = 0; i < NT; ++i) tr[i] = trans[i*NT + lane];
        alpha = startv[lane] + emi[(size_t)(b*SL)*NT + lane];
    }
    for (int tt = 1; tt < SL; ++tt){
        if (lane < NT) al[lane] = alpha;
        __syncthreads();
        if (lane < NT && tt < len){
            float mx = -1e30f;
            #pragma unroll
            for (int i = 0; i < NT; ++i) mx = fmaxf(mx, al[i] + tr[i]);
            float se = 0.f;
            #pragma unroll
            for (int i = 0; i < NT; ++i) se += __expf(al[i] + tr[i] - mx);
            alpha = mx + __logf(se) + emi[(size_t)(b*SL + tt)*NT + lane];
        }
        __syncthreads();
    }
    if (lane < NT) al[lane] = alpha + endv[lane];
    __syncthreads();
    if (lane == 0){
        float mx = -1e30f;
        for (int i = 0; i < NT; ++i) mx = fmaxf(mx, al[i]);
        float se = 0.f;
        for (int i = 0; i < NT; ++i) se += __expf(al[i] - mx);
        float den = mx + __logf(se);
        int t0g = tags[b*SL];
        float num = startv[t0g] + emi[(size_t)(b*SL)*NT + t0g] + npart;
        num += endv[tags[b*SL + len - 1]];
        atomicAdd(out_crf, -(num - den) * (1.0f/16.0f));
    }
}

// ---------------------------------------------------------------- token count
__global__ __launch_bounds__(256) void msum_k(const int* __restrict__ tokens, float* __restrict__ out_m)
{
    __shared__ int rr[4];
    int t = threadIdx.x;
    int cnt = 0;
    for (int i = t; i < NTOK; i += 256) cnt += (tokens[i] != 0) ? 1 : 0;
    #pragma unroll
    for (int off = 32; off > 0; off >>= 1) cnt += __shfl_down(cnt, off);
    if ((t & 63) == 0) rr[t >> 6] = cnt;
    __syncthreads();
    if (t == 0) out_m[0] = (float)(rr[0]+rr[1]+rr[2]+rr[3]);
}

// ---------------------------------------------------------------- fused uv->logits->BCE
__global__ __launch_bounds__(256) void sel_k(const float* __restrict__ U2,
                                             const float* __restrict__ V2,
                                             const float* __restrict__ uvb,
                                             const float* __restrict__ rel_emb,
                                             const int* __restrict__ gold,
                                             const int* __restrict__ tokens,
                                             float* __restrict__ out_sel)
{
    __shared__ float ret_s[RE][52];   // [k][r]
    __shared__ float pt_s[RE][68];    // [k][j]
    __shared__ float vb_s[RE];
    __shared__ float mk_s[64];
    __shared__ float red_s[4];
    const int jt = blockIdx.x, qi = blockIdx.y, b = blockIdx.z;
    const int t = threadIdx.x;
    if (tokens[b*SL + qi] == 0) return;   // pm row entirely zero
    if (t < 32){
        float4 v4 = *(const float4*)(V2 + (size_t)(b*SL + qi)*RE + t*4);
        float4 b4 = *(const float4*)(uvb + t*4);
        vb_s[t*4+0] = v4.x + b4.x; vb_s[t*4+1] = v4.y + b4.y;
        vb_s[t*4+2] = v4.z + b4.z; vb_s[t*4+3] = v4.w + b4.w;
    }
    if (t < 64) mk_s[t] = (tokens[b*SL + jt*64 + t] != 0) ? 1.f : 0.f;
    {
        int r = t & 63;
        for (int q = t >> 6; q < 32; q += 4){
            if (r < NR){
                float4 e4 = *(const float4*)(rel_emb + (size_t)r*RE + q*4);
                ret_s[q*4+0][r] = e4.x; ret_s[q*4+1][r] = e4.y;
                ret_s[q*4+2][r] = e4.z; ret_s[q*4+3][r] = e4.w;
            } else if (r < 64){
                ret_s[q*4+0][r] = 0.f; ret_s[q*4+1][r] = 0.f;
                ret_s[q*4+2][r] = 0.f; ret_s[q*4+3][r] = 0.f;
            }
        }
    }
    __syncthreads();
    {
        int j = t & 63;
        for (int q = t >> 6; q < 32; q += 4){
            float4 u4 = *(const float4*)(U2 + (size_t)(b*SL + jt*64 + j)*RE + q*4);
            pt_s[q*4+0][j] = fmaxf(u4.x + vb_s[q*4+0], 0.f);
            pt_s[q*4+1][j] = fmaxf(u4.y + vb_s[q*4+1], 0.f);
            pt_s[q*4+2][j] = fmaxf(u4.z + vb_s[q*4+2], 0.f);
            pt_s[q*4+3][j] = fmaxf(u4.w + vb_s[q*4+3], 0.f);
        }
    }
    __syncthreads();
    const int mj = (t & 15) * 4;   // j0
    const int nr = (t >> 4) * 4;   // r0
    float accv[4][4];
    #pragma unroll
    for (int i=0;i<4;++i){ accv[i][0]=0.f; accv[i][1]=0.f; accv[i][2]=0.f; accv[i][3]=0.f; }
    #pragma unroll 4
    for (int k = 0; k < RE; ++k){
        float4 aj = *(const float4*)&pt_s[k][mj];
        float4 br = *(const float4*)&ret_s[k][nr];
        float am[4] = {aj.x, aj.y, aj.z, aj.w};
        float bn[4] = {br.x, br.y, br.z, br.w};
        #pragma unroll
        for (int mm = 0; mm < 4; ++mm){
            #pragma unroll
            for (int nn = 0; nn < 4; ++nn)
                accv[mm][nn] += am[mm]*bn[nn];
        }
    }
    float lsum = 0.f;
    #pragma unroll
    for (int nn = 0; nn < 4; ++nn){
        int r = nr + nn;
        if (r < NR){
            const int* gp = gold + (size_t)((b*SL + qi)*NR + r)*SL + jt*64 + mj;
            #pragma unroll
            for (int mm = 0; mm < 4; ++mm){
                float l = accv[mm][nn];
                float g = (float)gp[mm];
                float bce = fmaxf(l, 0.f) - l*g + __logf(1.f + __expf(-fabsf(l)));
                lsum += bce * mk_s[mj + mm];
            }
        }
    }
    #pragma unroll
    for (int off = 32; off > 0; off >>= 1) lsum += __shfl_down(lsum, off);
    if ((t & 63) == 0) red_s[t >> 6] = lsum;
    __syncthreads();
    if (t == 0) atomicAdd(out_sel, red_s[0]+red_s[1]+red_s[2]+red_s[3]);
}

// ---------------------------------------------------------------- finalize
__global__ void finalize_k(const float* __restrict__ accum, float* __restrict__ out)
{
    if (threadIdx.x == 0 && blockIdx.x == 0) out[0] = accum[0] + accum[1] / accum[2];
}

// ---------------------------------------------------------------- launch
extern "C" void kernel_launch(void* const* d_in, const int* in_sizes, int n_in,
                              void* d_out, int out_size, void* d_ws, size_t ws_size,
                              hipStream_t stream)
{
    const int*   tokens    = (const int*)  d_in[0];
    const int*   bio_gold  = (const int*)  d_in[1];
    const int*   sel_gold  = (const int*)  d_in[2];
    // d_in[3] = is_train (unused)
    const float* word_emb  = (const float*)d_in[4];
    const float* rel_emb   = (const float*)d_in[5];
    const float* bio_emb   = (const float*)d_in[6];
    const float* w_ih_f    = (const float*)d_in[7];
    const float* w_hh_f    = (const float*)d_in[8];
    const float* b_ih_f    = (const float*)d_in[9];
    const float* b_hh_f    = (const float*)d_in[10];
    const float* w_ih_b    = (const float*)d_in[11];
    const float* w_hh_b    = (const float*)d_in[12];
    const float* b_ih_b    = (const float*)d_in[13];
    const float* b_hh_b    = (const float*)d_in[14];
    const float* emission_w= (const float*)d_in[15];
    const float* emission_b= (const float*)d_in[16];
    const float* sel_u_w   = (const float*)d_in[17];
    const float* sel_u_b   = (const float*)d_in[18];
    const float* sel_v_w   = (const float*)d_in[19];
    const float* sel_v_b   = (const float*)d_in[20];
    const float* sel_uv_w  = (const float*)d_in[21];
    const float* sel_uv_b  = (const float*)d_in[22];
    const float* crf_trans = (const float*)d_in[23];
    const float* crf_start = (const float*)d_in[24];
    const float* crf_end   = (const float*)d_in[25];
    (void)in_sizes; (void)n_in; (void)out_size; (void)ws_size;

    float* ws     = (float*)d_ws;
    float* emb    = ws;                         // 614400 (dead after xW gemms -> reused below)
    float* xwf    = emb    + (size_t)NTOK*ED;   // 4194304
    float* xwb    = xwf    + (size_t)NTOK*G4;   // 4194304
    float* hf_all = xwb    + (size_t)NTOK*G4;   // 1048576
    float* hb_all = hf_all + (size_t)NTOK*HD;   // 1048576
    float* oc     = hb_all + (size_t)NTOK*HD;   // 1179648
    float* emi    = oc     + (size_t)NTOK*OCD;  // 18432
    float* u_     = emi    + (size_t)NTOK*NT;   // 262144
    float* v_     = u_     + (size_t)NTOK*RE;   // 262144
    float* U2     = v_     + (size_t)NTOK*RE;   // 262144
    float* V2     = U2     + (size_t)NTOK*RE;   // 262144
    float* accum  = V2     + (size_t)NTOK*RE;   // [0]=crf, [1]=sel_sum, [2]=msum, [3]=pad

    // LSTM packed h exchange lives in the emb buffer (dead after the xW GEMMs):
    // 8 teams x 2 parities x 2048 u64 = 256 KB
    unsigned long long* hteam = (unsigned long long*)emb;

    hipMemsetAsync(accum, 0, 4*sizeof(float), stream);

    gather_emb_k<<<(NTOK*ED + 255)/256, 256, 0, stream>>>(tokens, word_emb, emb);

    dim3 gw(NTOK/128, G4/64);
    gemm_k<128><<<gw, 256, 0, stream>>>(emb, ED, w_ih_f, ED, xwf, G4, G4, ED, b_ih_f, b_hh_f, 0);
    gemm_k<128><<<gw, 256, 0, stream>>>(emb, ED, w_ih_b, ED, xwb, G4, G4, ED, b_ih_b, b_hh_b, 0);

    // emb is dead now; zero the packed h buffer (tag 0, value 0.0f == initial h)
    hipMemsetAsync(hteam, 0, (size_t)8*2*(4*HD)*sizeof(unsigned long long), stream);

    {
        const float *p_xwf = xwf, *p_xwb = xwb, *p_whf = w_hh_f, *p_whb = w_hh_b;
        unsigned long long* p_ht = hteam;
        float *p_hf = hf_all, *p_hb = hb_all;
        void* args[7] = {&p_xwf, &p_xwb, &p_whf, &p_whb, &p_ht, &p_hf, &p_hb};
        hipLaunchCooperativeKernel(lstm_k, dim3(256), dim3(256), args, 0u, stream);
    }

    combine_k<<<(NTOK*144 + 255)/256, 256, 0, stream>>>(hf_all, hb_all, bio_gold, bio_emb, oc);

    gemm_k<64><<<dim3(NTOK/64, 1), 256, 0, stream>>>(oc, OCD, emission_w, HD, emi, NT, NT, HD, emission_b, nullptr, 0);
    gemm_dual_k<64><<<dim3(NTOK/64, 2, 2), 256, 0, stream>>>(oc, oc, OCD, sel_u_w, sel_v_w, OCD,
                                                             u_, v_, RE, RE, OCD, sel_u_b, sel_v_b, 1);
    gemm_dual_k<64><<<dim3(NTOK/64, 2, 2), 256, 0, stream>>>(u_, v_, RE, sel_uv_w, sel_uv_w + RE, 2*RE,
                                                             U2, V2, RE, RE, RE, nullptr, nullptr, 0);

    crf_k<<<NB, 64, 0, stream>>>(emi, bio_gold, tokens, crf_trans, crf_start, crf_end, accum + 0);
    msum_k<<<1, 256, 0, stream>>>(tokens, accum + 2);
    sel_k<<<dim3(2, SL, NB), 256, 0, stream>>>(U2, V2, sel_uv_b, rel_emb, sel_gold, tokens, accum + 1);

    finalize_k<<<1, 1, 0, stream>>>(accum, (float*)d_out);
}

// Round 7
// 1045.125 us; speedup vs baseline: 2.1848x; 1.1363x over previous
//
#include <hip/hip_runtime.h>
#include <math.h>

// Problem dims
#define NB   16     // batch
#define SL   128    // seq len
#define ED   300    // word emb dim
#define HD   512    // lstm hidden
#define G4   2048   // 4*HD
#define NT   9      // tag count T
#define BE   64     // bio emb dim
#define RE   128    // REL_E
#define NR   50     // R
#define OCD  576    // HD + BE
#define NTOK 2048   // NB*SL

__device__ __forceinline__ float sigf(float x){ return 1.0f/(1.0f + __expf(-x)); }

// ---------------------------------------------------------------- gather emb
__global__ __launch_bounds__(256) void gather_emb_k(const int* __restrict__ tokens,
                                                    const float* __restrict__ word_emb,
                                                    float* __restrict__ emb)
{
    int idx = blockIdx.x*256 + threadIdx.x;
    if (idx < NTOK*ED){
        int row = idx / ED;
        int k = idx - row*ED;
        emb[idx] = word_emb[tokens[row]*ED + k];
    }
}

// ---------------------------------------------------------------- generic fp32 GEMM body
// C[m,n] = act( sum_k A[m,k]*B[n,k] + bias1[n] + bias2[n] )
template<int TM>
__device__ __forceinline__ void gemm_body(const float* __restrict__ A, int lda,
                                          const float* __restrict__ Bm, int ldb,
                                          float* __restrict__ C, int ldc,
                                          int N, int K,
                                          const float* __restrict__ bias1,
                                          const float* __restrict__ bias2,
                                          int do_relu, int m_blk, int n_blk)
{
    constexpr int TR = TM/16;                 // rows per thread (8 or 4)
    __shared__ float As[16][TM+4];            // [k][m]
    __shared__ float Bs[16][68];              // [k][n]
    const int t = threadIdx.x;
    const int tm = (t >> 4) * TR;
    const int tn = (t & 15) * 4;
    float acc[TR][4];
    #pragma unroll
    for (int i=0;i<TR;++i){ acc[i][0]=0.f; acc[i][1]=0.f; acc[i][2]=0.f; acc[i][3]=0.f; }

    const int kc = (K + 15) >> 4;
    for (int ck = 0; ck < kc; ++ck){
        const int k0 = ck << 4;
        __syncthreads();
        #pragma unroll
        for (int it = 0; it < TM/64; ++it){
            int task = t + it*256;
            int m = task >> 2, q = task & 3;
            int kk = k0 + q*4;
            float4 v = make_float4(0.f,0.f,0.f,0.f);
            const float* ap = A + (size_t)(m_blk + m)*lda + kk;
            if (kk + 3 < K) v = *(const float4*)ap;
            else {
                if (kk   < K) v.x = ap[0];
                if (kk+1 < K) v.y = ap[1];
                if (kk+2 < K) v.z = ap[2];
            }
            As[q*4+0][m] = v.x; As[q*4+1][m] = v.y; As[q*4+2][m] = v.z; As[q*4+3][m] = v.w;
        }
        {
            int n = t >> 2, q = t & 3;
            int kk = k0 + q*4;
            int gn = n_blk + n;
            float4 v = make_float4(0.f,0.f,0.f,0.f);
            if (gn < N){
                const float* bp = Bm + (size_t)gn*ldb + kk;
                if (kk + 3 < K) v = *(const float4*)bp;
                else {
                    if (kk   < K) v.x = bp[0];
                    if (kk+1 < K) v.y = bp[1];
                    if (kk+2 < K) v.z = bp[2];
                }
            }
            Bs[q*4+0][n] = v.x; Bs[q*4+1][n] = v.y; Bs[q*4+2][n] = v.z; Bs[q*4+3][n] = v.w;
        }
        __syncthreads();
        #pragma unroll
        for (int k = 0; k < 16; ++k){
            float4 b4 = *(const float4*)&Bs[k][tn];
            float bn[4] = {b4.x, b4.y, b4.z, b4.w};
            #pragma unroll
            for (int i = 0; i < TR/4; ++i){
                float4 a4 = *(const float4*)&As[k][tm + i*4];
                float am[4] = {a4.x, a4.y, a4.z, a4.w};
                #pragma unroll
                for (int mm = 0; mm < 4; ++mm){
                    #pragma unroll
                    for (int nn = 0; nn < 4; ++nn)
                        acc[i*4+mm][nn] += am[mm]*bn[nn];
                }
            }
        }
    }
    float bv[4];
    #pragma unroll
    for (int nn=0;nn<4;++nn){
        int gn = n_blk + tn + nn;
        float bb = 0.f;
        if (gn < N){
            if (bias1) bb += bias1[gn];
            if (bias2) bb += bias2[gn];
        }
        bv[nn] = bb;
    }
    bool vec = ((ldc & 3) == 0) && (n_blk + tn + 3 < N);
    #pragma unroll
    for (int mm = 0; mm < TR; ++mm){
        int gm = m_blk + tm + mm;
        float r0 = acc[mm][0] + bv[0];
        float r1 = acc[mm][1] + bv[1];
        float r2 = acc[mm][2] + bv[2];
        float r3 = acc[mm][3] + bv[3];
        if (do_relu){ r0=fmaxf(r0,0.f); r1=fmaxf(r1,0.f); r2=fmaxf(r2,0.f); r3=fmaxf(r3,0.f); }
        if (vec){
            *(float4*)(C + (size_t)gm*ldc + n_blk + tn) = make_float4(r0,r1,r2,r3);
        } else {
            int gn = n_blk + tn;
            if (gn   < N) C[(size_t)gm*ldc + gn  ] = r0;
            if (gn+1 < N) C[(size_t)gm*ldc + gn+1] = r1;
            if (gn+2 < N) C[(size_t)gm*ldc + gn+2] = r2;
            if (gn+3 < N) C[(size_t)gm*ldc + gn+3] = r3;
        }
    }
}

template<int TM>
__global__ __launch_bounds__(256) void gemm_k(const float* __restrict__ A, int lda,
                                              const float* __restrict__ Bm, int ldb,
                                              float* __restrict__ C, int ldc,
                                              int N, int K,
                                              const float* __restrict__ bias1,
                                              const float* __restrict__ bias2,
                                              int do_relu)
{
    gemm_body<TM>(A, lda, Bm, ldb, C, ldc, N, K, bias1, bias2, do_relu,
                  blockIdx.x * TM, blockIdx.y * 64);
}

// dual: blockIdx.z selects (A,B,C,bias) set — merges two same-shape GEMMs into one launch
template<int TM>
__global__ __launch_bounds__(256) void gemm_dual_k(const float* __restrict__ A0, const float* __restrict__ A1, int lda,
                                                   const float* __restrict__ B0, const float* __restrict__ B1, int ldb,
                                                   float* __restrict__ C0, float* __restrict__ C1, int ldc,
                                                   int N, int K,
                                                   const float* __restrict__ bias0, const float* __restrict__ bias1,
                                                   int do_relu)
{
    const int z = blockIdx.z;
    gemm_body<TM>(z ? A1 : A0, lda, z ? B1 : B0, ldb, z ? C1 : C0, ldc, N, K,
                  z ? bias1 : bias0, nullptr, do_relu, blockIdx.x * TM, blockIdx.y * 64);
}

// ---------------------------------------------------------------- team-parallel LSTM
// 8 teams of 32 wgs; team = (dir = team&1, batches [(team>>1)*4, +4)). wg rank owns
// hidden [rank*16,+16) (64 gate rows); weights in VGPRs (fully unrolled indices).
// Thread = (row-group rg = t&31 -> 2 rows, k-chunk kc = t>>5 -> 64 k); wave wv
// stages only its k-span [wv*128,+128) into wave-private LDS (no stage barrier).
// R7 fix: the tag-spin polls ALL 8 slots unconditionally each round -> 8 loads
// issued back-to-back in ONE basic block (single vmcnt drain, ~1 LLC latency per
// round) instead of R6's 8 serially-waited loads under divergent ifs (~8 LLC
// latencies per round = the 13k-cycle step).
__global__ __launch_bounds__(256, 1) void lstm_k(const float* __restrict__ xwf,
                                                 const float* __restrict__ xwb,
                                                 const float* __restrict__ whhf,
                                                 const float* __restrict__ whhb,
                                                 unsigned long long* __restrict__ hteam, // [8][2][2048] u64
                                                 float* __restrict__ hf_all,
                                                 float* __restrict__ hb_all)
{
    __shared__ __align__(16) float h_s[4*HD];      // 8 KB  [b][512]
    __shared__ __align__(16) float part[8*256];    // 8 KB  [kc][row*4+b]
    __shared__ float gates_s[256];                 // [row*4 + b]
    __shared__ float cst[64];                      // [b*16 + hl]
    const int wg   = blockIdx.x;
    const int team = wg >> 5;
    const int rank = wg & 31;
    const int d    = team & 1;
    const int b0   = (team >> 1) * 4;
    const int t    = threadIdx.x;
    const int wv   = t >> 6;                       // wave 0..3
    const int lane = t & 63;
    const int rg   = t & 31;                       // row-group -> rows rg*2, rg*2+1
    const int kc   = t >> 5;                       // k-chunk 0..7 (64 k each)
    const int lr0  = rg*2, lr1 = rg*2 + 1;         // local gate rows
    const int grow0 = (lr0 >> 4)*HD + rank*16 + (lr0 & 15);
    const int grow1 = (lr1 >> 4)*HD + rank*16 + (lr1 & 15);
    const float* whh = d ? whhb : whhf;
    const float* xw  = d ? xwb  : xwf;
    float* hall      = d ? hb_all : hf_all;
    unsigned long long* hT = hteam + (size_t)team*2*(4*HD);

    // ---- one-time: 2 rows x 64 k weights into registers (32 float4 = 128 VGPRs) ----
    float4 w0[16], w1[16];
    {
        const float* wp0 = whh + (size_t)grow0*HD + kc*64;
        const float* wp1 = whh + (size_t)grow1*HD + kc*64;
        #pragma unroll
        for (int q = 0; q < 16; ++q){ w0[q] = *(const float4*)(wp0 + q*4);
                                      w1[q] = *(const float4*)(wp1 + q*4); }
    }
    // reduce mapping: t -> (row rrow, batch rb); gates_s[t] corresponds to it
    const int rrow = t >> 2, rb = t & 3;
    const int growr = (rrow >> 4)*HD + rank*16 + (rrow & 15);
    // activation mapping: t<64 -> (hid-local ahl, batch ab)
    const int ahl = t & 15, ab = t >> 4;
    const int hidx_a = rank*16 + ahl;
    // staging offsets: wave wv stages k-span [wv*128, +128) for all 4 batches
    // idx(i) = (i>>1)*512 + wv*128 + (i&1)*64 + lane
    const int sb = wv*128 + lane;

    if (t < 64) cst[t] = 0.f;
    __syncthreads();

    int par = 0;
    for (int s = 0; s < SL; ++s){
        const int tx = d ? (SL-1 - s) : s;
        // xw value for the reduce phase (issued early, hides under the spin)
        const float xval = xw[(size_t)((b0 + rb)*SL + tx)*G4 + growr];
        // ---- 1. per-wave staging: poll ALL 8 slots per round (pipelined loads) ----
        {
            const unsigned long long* src = hT + (size_t)par*(4*HD);
            unsigned long long v[8];
            const unsigned want = (unsigned)s;
            for (;;){
                #pragma unroll
                for (int i = 0; i < 8; ++i)
                    v[i] = __hip_atomic_load(&src[(i>>1)*512 + (i&1)*64 + sb],
                                             __ATOMIC_RELAXED, __HIP_MEMORY_SCOPE_AGENT);
                bool ok = true;
                #pragma unroll
                for (int i = 0; i < 8; ++i) ok = ok && ((unsigned)(v[i] >> 32) == want);
                if (ok) break;
                __builtin_amdgcn_s_sleep(1);
            }
            #pragma unroll
            for (int i = 0; i < 8; ++i)
                h_s[(i>>1)*HD + (i&1)*64 + sb] = __uint_as_float((unsigned)v[i]);
        }
        // NO barrier: each wave reads only the h_s region it just wrote.
        // ---- 2. partial dots: 2 rows x 4 batches x 64 k ----
        {
            float a0[4] = {0.f,0.f,0.f,0.f};
            float a1[4] = {0.f,0.f,0.f,0.f};
            #pragma unroll
            for (int q = 0; q < 16; ++q){
                float4 wa = w0[q], wb = w1[q];
                #pragma unroll
                for (int b = 0; b < 4; ++b){
                    float4 h4 = *(const float4*)(h_s + b*HD + kc*64 + q*4);
                    a0[b] += wa.x*h4.x + wa.y*h4.y + wa.z*h4.z + wa.w*h4.w;
                    a1[b] += wb.x*h4.x + wb.y*h4.y + wb.z*h4.z + wb.w*h4.w;
                }
            }
            *(float4*)&part[kc*256 + lr0*4] = make_float4(a0[0],a0[1],a0[2],a0[3]);
            *(float4*)&part[kc*256 + lr1*4] = make_float4(a1[0],a1[1],a1[2],a1[3]);
        }
        __syncthreads();
        // ---- 3. reduce 8 k-chunks + add xW (biases folded into xW) ----
        {
            float gsum = 0.f;
            #pragma unroll
            for (int c = 0; c < 8; ++c) gsum += part[c*256 + t];
            gates_s[t] = gsum + xval;
        }
        __syncthreads();
        // ---- 4. activation: 16 hidden x 4 batches; packed (tag|value) store ----
        if (t < 64){
            float gi = gates_s[((0*16) + ahl)*4 + ab];
            float gf = gates_s[((1*16) + ahl)*4 + ab];
            float gc = gates_s[((2*16) + ahl)*4 + ab];
            float gov = gates_s[((3*16) + ahl)*4 + ab];
            float cp = cst[t];
            float cn = sigf(gf)*cp + sigf(gi)*tanhf(gc);
            float hn = sigf(gov)*tanhf(cn);
            cst[t] = cn;
            unsigned long long pk = ((unsigned long long)(unsigned)(s+1) << 32)
                                  | (unsigned long long)__float_as_uint(hn);
            __hip_atomic_store(&hT[(size_t)(par^1)*(4*HD) + ab*HD + hidx_a], pk,
                               __ATOMIC_RELAXED, __HIP_MEMORY_SCOPE_AGENT);
            hall[(size_t)((b0 + ab)*SL + tx)*HD + hidx_a] = hn;
        }
        // safe without a trailing barrier: next part-write happens only after this
        // step's post-reduce barrier; gates_s rewrite only after next sync1.
        par ^= 1;
    }
}

// ---------------------------------------------------------------- combine o | bio_emb
__global__ __launch_bounds__(256) void combine_k(const float* __restrict__ hf,
                                                 const float* __restrict__ hb,
                                                 const int* __restrict__ bio_gold,
                                                 const float* __restrict__ bio_emb,
                                                 float* __restrict__ oc)
{
    int idx = blockIdx.x*256 + threadIdx.x;      // float4 index over NTOK*144
    if (idx >= NTOK*144) return;
    int row = idx / 144;
    int c4 = (idx - row*144) * 4;
    float4 v;
    if (c4 < HD){
        float4 a = *(const float4*)(hf + (size_t)row*HD + c4);
        float4 b = *(const float4*)(hb + (size_t)row*HD + c4);
        v = make_float4(0.5f*(a.x+b.x), 0.5f*(a.y+b.y), 0.5f*(a.z+b.z), 0.5f*(a.w+b.w));
    } else {
        int bg = bio_gold[row];
        v = *(const float4*)(bio_emb + bg*BE + (c4 - HD));
    }
    *(float4*)(oc + (size_t)row*OCD + c4) = v;
}

// ---------------------------------------------------------------- CRF NLL
__global__ __launch_bounds__(64) void crf_k(const float* __restrict__ emi,
                                            const int* __restrict__ tags,
                                            const int* __restrict__ tokens,
                                            const float* __restrict__ trans,
                                            const float* __restrict__ startv,
                                            const float* __restrict__ endv,
                                            float* __restrict__ out_crf)
{
    __shared__ float al[16];
    const int b = blockIdx.x, lane = threadIdx.x;
    unsigned long long m0 = __ballot(tokens[b*SL + lane] != 0);
    unsigned long long m1 = __ballot(tokens[b*SL + 64 + lane] != 0);
    const int len = __popcll(m0) + __popcll(m1);
    float npart = 0.f;
    #pragma unroll
    for (int half = 0; half < 2; ++half){
        int tt = lane + half*64;
        if (tt >= 1 && tt < len){
            int tp = tags[b*SL + tt - 1], tc = tags[b*SL + tt];
            npart += trans[tp*NT + tc] + emi[(size_t)(b*SL + tt)*NT + tc];
        }
    }
    #pragma unroll
    for (int off = 32; off > 0; off >>= 1) npart += __shfl_down(npart, off);
    float tr[NT]; float alpha = -1e30f;
    if (lane < NT){
        #pragma unroll
        for (int i = 0; i < NT; ++i) tr[i] = trans[i*NT + lane];
        alpha = startv[lane] + emi[(size_t)(b*SL)*NT + lane];
    }
    for (int tt = 1; tt < SL; ++tt){
        if (lane < NT) al[lane] = alpha;
        __syncthreads();
        if (lane < NT && tt < len){
            float mx = -1e30f;
            #pragma unroll
            for (int i = 0; i < NT; ++i) mx = fmaxf(mx, al[i] + tr[i]);
            float se = 0.f;
            #pragma unroll
            for (int i = 0; i < NT; ++i) se += __expf(al[i] + tr[i] - mx);
            alpha = mx + __logf(se) + emi[(size_t)(b*SL + tt)*NT + lane];
        }
        __syncthreads();
    }
    if (lane < NT) al[lane] = alpha + endv[lane];
    __syncthreads();
    if (lane == 0){
        float mx = -1e30f;
        for (int i = 0; i < NT; ++i) mx = fmaxf(mx, al[i]);
        float se = 0.f;
        for (int i = 0; i < NT; ++i) se += __expf(al[i] - mx);
        float den = mx + __logf(se);
        int t0g = tags[b*SL];
        float num = startv[t0g] + emi[(size_t)(b*SL)*NT + t0g] + npart;
        num += endv[tags[b*SL + len - 1]];
        atomicAdd(out_crf, -(num - den) * (1.0f/16.0f));
    }
}

// ---------------------------------------------------------------- token count
__global__ __launch_bounds__(256) void msum_k(const int* __restrict__ tokens, float* __restrict__ out_m)
{
    __shared__ int rr[4];
    int t = threadIdx.x;
    int cnt = 0;
    for (int i = t; i < NTOK; i += 256) cnt += (tokens[i] != 0) ? 1 : 0;
    #pragma unroll
    for (int off = 32; off > 0; off >>= 1) cnt += __shfl_down(cnt, off);
    if ((t & 63) == 0) rr[t >> 6] = cnt;
    __syncthreads();
    if (t == 0) out_m[0] = (float)(rr[0]+rr[1]+rr[2]+rr[3]);
}

// ---------------------------------------------------------------- fused uv->logits->BCE
__global__ __launch_bounds__(256) void sel_k(const float* __restrict__ U2,
                                             const float* __restrict__ V2,
                                             const float* __restrict__ uvb,
                                             const float* __restrict__ rel_emb,
                                             const int* __restrict__ gold,
                                             const int* __restrict__ tokens,
                                             float* __restrict__ out_sel)
{
    __shared__ float ret_s[RE][52];   // [k][r]
    __shared__ float pt_s[RE][68];    // [k][j]
    __shared__ float vb_s[RE];
    __shared__ float mk_s[64];
    __shared__ float red_s[4];
    const int jt = blockIdx.x, qi = blockIdx.y, b = blockIdx.z;
    const int t = threadIdx.x;
    if (tokens[b*SL + qi] == 0) return;   // pm row entirely zero
    if (t < 32){
        float4 v4 = *(const float4*)(V2 + (size_t)(b*SL + qi)*RE + t*4);
        float4 b4 = *(const float4*)(uvb + t*4);
        vb_s[t*4+0] = v4.x + b4.x; vb_s[t*4+1] = v4.y + b4.y;
        vb_s[t*4+2] = v4.z + b4.z; vb_s[t*4+3] = v4.w + b4.w;
    }
    if (t < 64) mk_s[t] = (tokens[b*SL + jt*64 + t] != 0) ? 1.f : 0.f;
    {
        int r = t & 63;
        for (int q = t >> 6; q < 32; q += 4){
            if (r < NR){
                float4 e4 = *(const float4*)(rel_emb + (size_t)r*RE + q*4);
                ret_s[q*4+0][r] = e4.x; ret_s[q*4+1][r] = e4.y;
                ret_s[q*4+2][r] = e4.z; ret_s[q*4+3][r] = e4.w;
            } else if (r < 64){
                ret_s[q*4+0][r] = 0.f; ret_s[q*4+1][r] = 0.f;
                ret_s[q*4+2][r] = 0.f; ret_s[q*4+3][r] = 0.f;
            }
        }
    }
    __syncthreads();
    {
        int j = t & 63;
        for (int q = t >> 6; q < 32; q += 4){
            float4 u4 = *(const float4*)(U2 + (size_t)(b*SL + jt*64 + j)*RE + q*4);
            pt_s[q*4+0][j] = fmaxf(u4.x + vb_s[q*4+0], 0.f);
            pt_s[q*4+1][j] = fmaxf(u4.y + vb_s[q*4+1], 0.f);
            pt_s[q*4+2][j] = fmaxf(u4.z + vb_s[q*4+2], 0.f);
            pt_s[q*4+3][j] = fmaxf(u4.w + vb_s[q*4+3], 0.f);
        }
    }
    __syncthreads();
    const int mj = (t & 15) * 4;   // j0
    const int nr = (t >> 4) * 4;   // r0
    float accv[4][4];
    #pragma unroll
    for (int i=0;i<4;++i){ accv[i][0]=0.f; accv[i][1]=0.f; accv[i][2]=0.f; accv[i][3]=0.f; }
    #pragma unroll 4
    for (int k = 0; k < RE; ++k){
        float4 aj = *(const float4*)&pt_s[k][mj];
        float4 br = *(const float4*)&ret_s[k][nr];
        float am[4] = {aj.x, aj.y, aj.z, aj.w};
        float bn[4] = {br.x, br.y, br.z, br.w};
        #pragma unroll
        for (int mm = 0; mm < 4; ++mm){
            #pragma unroll
            for (int nn = 0; nn < 4; ++nn)
                accv[mm][nn] += am[mm]*bn[nn];
        }
    }
    float lsum = 0.f;
    #pragma unroll
    for (int nn = 0; nn < 4; ++nn){
        int r = nr + nn;
        if (r < NR){
            const int* gp = gold + (size_t)((b*SL + qi)*NR + r)*SL + jt*64 + mj;
            #pragma unroll
            for (int mm = 0; mm < 4; ++mm){
                float l = accv[mm][nn];
                float g = (float)gp[mm];
                float bce = fmaxf(l, 0.f) - l*g + __logf(1.f + __expf(-fabsf(l)));
                lsum += bce * mk_s[mj + mm];
            }
        }
    }
    #pragma unroll
    for (int off = 32; off > 0; off >>= 1) lsum += __shfl_down(lsum, off);
    if ((t & 63) == 0) red_s[t >> 6] = lsum;
    __syncthreads();
    if (t == 0) atomicAdd(out_sel, red_s[0]+red_s[1]+red_s[2]+red_s[3]);
}

// ---------------------------------------------------------------- finalize
__global__ void finalize_k(const float* __restrict__ accum, float* __restrict__ out)
{
    if (threadIdx.x == 0 && blockIdx.x == 0) out[0] = accum[0] + accum[1] / accum[2];
}

// ---------------------------------------------------------------- launch
extern "C" void kernel_launch(void* const* d_in, const int* in_sizes, int n_in,
                              void* d_out, int out_size, void* d_ws, size_t ws_size,
                              hipStream_t stream)
{
    const int*   tokens    = (const int*)  d_in[0];
    const int*   bio_gold  = (const int*)  d_in[1];
    const int*   sel_gold  = (const int*)  d_in[2];
    // d_in[3] = is_train (unused)
    const float* word_emb  = (const float*)d_in[4];
    const float* rel_emb   = (const float*)d_in[5];
    const float* bio_emb   = (const float*)d_in[6];
    const float* w_ih_f    = (const float*)d_in[7];
    const float* w_hh_f    = (const float*)d_in[8];
    const float* b_ih_f    = (const float*)d_in[9];
    const float* b_hh_f    = (const float*)d_in[10];
    const float* w_ih_b    = (const float*)d_in[11];
    const float* w_hh_b    = (const float*)d_in[12];
    const float* b_ih_b    = (const float*)d_in[13];
    const float* b_hh_b    = (const float*)d_in[14];
    const float* emission_w= (const float*)d_in[15];
    const float* emission_b= (const float*)d_in[16];
    const float* sel_u_w   = (const float*)d_in[17];
    const float* sel_u_b   = (const float*)d_in[18];
    const float* sel_v_w   = (const float*)d_in[19];
    const float* sel_v_b   = (const float*)d_in[20];
    const float* sel_uv_w  = (const float*)d_in[21];
    const float* sel_uv_b  = (const float*)d_in[22];
    const float* crf_trans = (const float*)d_in[23];
    const float* crf_start = (const float*)d_in[24];
    const float* crf_end   = (const float*)d_in[25];
    (void)in_sizes; (void)n_in; (void)out_size; (void)ws_size;

    float* ws     = (float*)d_ws;
    float* emb    = ws;                         // 614400 (dead after xW gemms -> reused below)
    float* xwf    = emb    + (size_t)NTOK*ED;   // 4194304
    float* xwb    = xwf    + (size_t)NTOK*G4;   // 4194304
    float* hf_all = xwb    + (size_t)NTOK*G4;   // 1048576
    float* hb_all = hf_all + (size_t)NTOK*HD;   // 1048576
    float* oc     = hb_all + (size_t)NTOK*HD;   // 1179648
    float* emi    = oc     + (size_t)NTOK*OCD;  // 18432
    float* u_     = emi    + (size_t)NTOK*NT;   // 262144
    float* v_     = u_     + (size_t)NTOK*RE;   // 262144
    float* U2     = v_     + (size_t)NTOK*RE;   // 262144
    float* V2     = U2     + (size_t)NTOK*RE;   // 262144
    float* accum  = V2     + (size_t)NTOK*RE;   // [0]=crf, [1]=sel_sum, [2]=msum, [3]=pad

    // LSTM packed h exchange lives in the emb buffer (dead after the xW GEMMs):
    // 8 teams x 2 parities x 2048 u64 = 256 KB
    unsigned long long* hteam = (unsigned long long*)emb;

    hipMemsetAsync(accum, 0, 4*sizeof(float), stream);

    gather_emb_k<<<(NTOK*ED + 255)/256, 256, 0, stream>>>(tokens, word_emb, emb);

    dim3 gw(NTOK/128, G4/64);
    gemm_k<128><<<gw, 256, 0, stream>>>(emb, ED, w_ih_f, ED, xwf, G4, G4, ED, b_ih_f, b_hh_f, 0);
    gemm_k<128><<<gw, 256, 0, stream>>>(emb, ED, w_ih_b, ED, xwb, G4, G4, ED, b_ih_b, b_hh_b, 0);

    // emb is dead now; zero the packed h buffer (tag 0, value 0.0f == initial h)
    hipMemsetAsync(hteam, 0, (size_t)8*2*(4*HD)*sizeof(unsigned long long), stream);

    {
        const float *p_xwf = xwf, *p_xwb = xwb, *p_whf = w_hh_f, *p_whb = w_hh_b;
        unsigned long long* p_ht = hteam;
        float *p_hf = hf_all, *p_hb = hb_all;
        void* args[7] = {&p_xwf, &p_xwb, &p_whf, &p_whb, &p_ht, &p_hf, &p_hb};
        hipLaunchCooperativeKernel(lstm_k, dim3(256), dim3(256), args, 0u, stream);
    }

    combine_k<<<(NTOK*144 + 255)/256, 256, 0, stream>>>(hf_all, hb_all, bio_gold, bio_emb, oc);

    gemm_k<64><<<dim3(NTOK/64, 1), 256, 0, stream>>>(oc, OCD, emission_w, HD, emi, NT, NT, HD, emission_b, nullptr, 0);
    gemm_dual_k<64><<<dim3(NTOK/64, 2, 2), 256, 0, stream>>>(oc, oc, OCD, sel_u_w, sel_v_w, OCD,
                                                             u_, v_, RE, RE, OCD, sel_u_b, sel_v_b, 1);
    gemm_dual_k<64><<<dim3(NTOK/64, 2, 2), 256, 0, stream>>>(u_, v_, RE, sel_uv_w, sel_uv_w + RE, 2*RE,
                                                             U2, V2, RE, RE, RE, nullptr, nullptr, 0);

    crf_k<<<NB, 64, 0, stream>>>(emi, bio_gold, tokens, crf_trans, crf_start, crf_end, accum + 0);
    msum_k<<<1, 256, 0, stream>>>(tokens, accum + 2);
    sel_k<<<dim3(2, SL, NB), 256, 0, stream>>>(U2, V2, sel_uv_b, rel_emb, sel_gold, tokens, accum + 1);

    finalize_k<<<1, 1, 0, stream>>>(accum, (float*)d_out);
}

// Round 8
// 999.556 us; speedup vs baseline: 2.2844x; 1.0456x over previous
//
#include <hip/hip_runtime.h>
#include <math.h>

// Problem dims
#define NB   16     // batch
#define SL   128    // seq len
#define ED   300    // word emb dim
#define HD   512    // lstm hidden
#define G4   2048   // 4*HD
#define NT   9      // tag count T
#define BE   64     // bio emb dim
#define RE   128    // REL_E
#define NR   50     // R
#define OCD  576    // HD + BE
#define NTOK 2048   // NB*SL

__device__ __forceinline__ float sigf(float x){ return 1.0f/(1.0f + __expf(-x)); }

// ---------------------------------------------------------------- generic fp32 GEMM body
template<int TM>
__device__ __forceinline__ void gemm_body(const float* __restrict__ A, int lda,
                                          const float* __restrict__ Bm, int ldb,
                                          float* __restrict__ C, int ldc,
                                          int N, int K,
                                          const float* __restrict__ bias1,
                                          const float* __restrict__ bias2,
                                          int do_relu, int m_blk, int n_blk)
{
    constexpr int TR = TM/16;
    __shared__ float As[16][TM+4];
    __shared__ float Bs[16][68];
    const int t = threadIdx.x;
    const int tm = (t >> 4) * TR;
    const int tn = (t & 15) * 4;
    float acc[TR][4];
    #pragma unroll
    for (int i=0;i<TR;++i){ acc[i][0]=0.f; acc[i][1]=0.f; acc[i][2]=0.f; acc[i][3]=0.f; }

    const int kc = (K + 15) >> 4;
    for (int ck = 0; ck < kc; ++ck){
        const int k0 = ck << 4;
        __syncthreads();
        #pragma unroll
        for (int it = 0; it < TM/64; ++it){
            int task = t + it*256;
            int m = task >> 2, q = task & 3;
            int kk = k0 + q*4;
            float4 v = make_float4(0.f,0.f,0.f,0.f);
            const float* ap = A + (size_t)(m_blk + m)*lda + kk;
            if (kk + 3 < K) v = *(const float4*)ap;
            else {
                if (kk   < K) v.x = ap[0];
                if (kk+1 < K) v.y = ap[1];
                if (kk+2 < K) v.z = ap[2];
            }
            As[q*4+0][m] = v.x; As[q*4+1][m] = v.y; As[q*4+2][m] = v.z; As[q*4+3][m] = v.w;
        }
        {
            int n = t >> 2, q = t & 3;
            int kk = k0 + q*4;
            int gn = n_blk + n;
            float4 v = make_float4(0.f,0.f,0.f,0.f);
            if (gn < N){
                const float* bp = Bm + (size_t)gn*ldb + kk;
                if (kk + 3 < K) v = *(const float4*)bp;
                else {
                    if (kk   < K) v.x = bp[0];
                    if (kk+1 < K) v.y = bp[1];
                    if (kk+2 < K) v.z = bp[2];
                }
            }
            Bs[q*4+0][n] = v.x; Bs[q*4+1][n] = v.y; Bs[q*4+2][n] = v.z; Bs[q*4+3][n] = v.w;
        }
        __syncthreads();
        #pragma unroll
        for (int k = 0; k < 16; ++k){
            float4 b4 = *(const float4*)&Bs[k][tn];
            float bn[4] = {b4.x, b4.y, b4.z, b4.w};
            #pragma unroll
            for (int i = 0; i < TR/4; ++i){
                float4 a4 = *(const float4*)&As[k][tm + i*4];
                float am[4] = {a4.x, a4.y, a4.z, a4.w};
                #pragma unroll
                for (int mm = 0; mm < 4; ++mm){
                    #pragma unroll
                    for (int nn = 0; nn < 4; ++nn)
                        acc[i*4+mm][nn] += am[mm]*bn[nn];
                }
            }
        }
    }
    float bv[4];
    #pragma unroll
    for (int nn=0;nn<4;++nn){
        int gn = n_blk + tn + nn;
        float bb = 0.f;
        if (gn < N){
            if (bias1) bb += bias1[gn];
            if (bias2) bb += bias2[gn];
        }
        bv[nn] = bb;
    }
    bool vec = ((ldc & 3) == 0) && (n_blk + tn + 3 < N);
    #pragma unroll
    for (int mm = 0; mm < TR; ++mm){
        int gm = m_blk + tm + mm;
        float r0 = acc[mm][0] + bv[0];
        float r1 = acc[mm][1] + bv[1];
        float r2 = acc[mm][2] + bv[2];
        float r3 = acc[mm][3] + bv[3];
        if (do_relu){ r0=fmaxf(r0,0.f); r1=fmaxf(r1,0.f); r2=fmaxf(r2,0.f); r3=fmaxf(r3,0.f); }
        if (vec){
            *(float4*)(C + (size_t)gm*ldc + n_blk + tn) = make_float4(r0,r1,r2,r3);
        } else {
            int gn = n_blk + tn;
            if (gn   < N) C[(size_t)gm*ldc + gn  ] = r0;
            if (gn+1 < N) C[(size_t)gm*ldc + gn+1] = r1;
            if (gn+2 < N) C[(size_t)gm*ldc + gn+2] = r2;
            if (gn+3 < N) C[(size_t)gm*ldc + gn+3] = r3;
        }
    }
}

template<int TM>
__global__ __launch_bounds__(256) void gemm_k(const float* __restrict__ A, int lda,
                                              const float* __restrict__ Bm, int ldb,
                                              float* __restrict__ C, int ldc,
                                              int N, int K,
                                              const float* __restrict__ bias1,
                                              const float* __restrict__ bias2,
                                              int do_relu)
{
    gemm_body<TM>(A, lda, Bm, ldb, C, ldc, N, K, bias1, bias2, do_relu,
                  blockIdx.x * TM, blockIdx.y * 64);
}

template<int TM>
__global__ __launch_bounds__(256) void gemm_dual_k(const float* __restrict__ A0, const float* __restrict__ A1, int lda,
                                                   const float* __restrict__ B0, const float* __restrict__ B1, int ldb,
                                                   float* __restrict__ C0, float* __restrict__ C1, int ldc,
                                                   int N, int K,
                                                   const float* __restrict__ bias0, const float* __restrict__ bias1,
                                                   int do_relu)
{
    const int z = blockIdx.z;
    gemm_body<TM>(z ? A1 : A0, lda, z ? B1 : B0, ldb, z ? C1 : C0, ldc, N, K,
                  z ? bias1 : bias0, nullptr, do_relu, blockIdx.x * TM, blockIdx.y * 64);
}

// ---------------------------------------------------------------- xW GEMM with fused token-gather
// A[m,k] = word_emb[tokens[m]*ED + k]; z selects direction (weights/bias/output).
__global__ __launch_bounds__(256) void gemm_emb_k(const int* __restrict__ tokens,
                                                  const float* __restrict__ word_emb,
                                                  const float* __restrict__ B0, const float* __restrict__ B1,
                                                  float* __restrict__ C0, float* __restrict__ C1,
                                                  const float* __restrict__ bi0a, const float* __restrict__ bi0b,
                                                  const float* __restrict__ bi1a, const float* __restrict__ bi1b)
{
    __shared__ float As[16][132];
    __shared__ float Bs[16][68];
    const int z = blockIdx.z;
    const float* Bm = z ? B1 : B0;
    float* C       = z ? C1 : C0;
    const float* ba = z ? bi1a : bi0a;
    const float* bb = z ? bi1b : bi0b;
    const int t = threadIdx.x;
    const int m_blk = blockIdx.x * 128;
    const int n_blk = blockIdx.y * 64;
    const int tm = (t >> 4) * 8;
    const int tn = (t & 15) * 4;
    float acc[8][4];
    #pragma unroll
    for (int i=0;i<8;++i){ acc[i][0]=0.f; acc[i][1]=0.f; acc[i][2]=0.f; acc[i][3]=0.f; }

    for (int ck = 0; ck < 19; ++ck){
        const int k0 = ck << 4;
        __syncthreads();
        #pragma unroll
        for (int it = 0; it < 2; ++it){
            int task = t + it*256;
            int m = task >> 2, q = task & 3;
            int kk = k0 + q*4;
            const int tok = tokens[m_blk + m];
            const float* ap = word_emb + (size_t)tok*ED + kk;
            float4 v = make_float4(0.f,0.f,0.f,0.f);
            if (kk + 3 < ED) v = *(const float4*)ap;
            else {
                if (kk   < ED) v.x = ap[0];
                if (kk+1 < ED) v.y = ap[1];
                if (kk+2 < ED) v.z = ap[2];
            }
            As[q*4+0][m] = v.x; As[q*4+1][m] = v.y; As[q*4+2][m] = v.z; As[q*4+3][m] = v.w;
        }
        {
            int n = t >> 2, q = t & 3;
            int kk = k0 + q*4;
            const float* bp = Bm + (size_t)(n_blk + n)*ED + kk;
            float4 v = make_float4(0.f,0.f,0.f,0.f);
            if (kk + 3 < ED) v = *(const float4*)bp;
            else {
                if (kk   < ED) v.x = bp[0];
                if (kk+1 < ED) v.y = bp[1];
                if (kk+2 < ED) v.z = bp[2];
            }
            Bs[q*4+0][n] = v.x; Bs[q*4+1][n] = v.y; Bs[q*4+2][n] = v.z; Bs[q*4+3][n] = v.w;
        }
        __syncthreads();
        #pragma unroll
        for (int k = 0; k < 16; ++k){
            float4 b4 = *(const float4*)&Bs[k][tn];
            float bn[4] = {b4.x, b4.y, b4.z, b4.w};
            #pragma unroll
            for (int i = 0; i < 2; ++i){
                float4 a4 = *(const float4*)&As[k][tm + i*4];
                float am[4] = {a4.x, a4.y, a4.z, a4.w};
                #pragma unroll
                for (int mm = 0; mm < 4; ++mm){
                    #pragma unroll
                    for (int nn = 0; nn < 4; ++nn)
                        acc[i*4+mm][nn] += am[mm]*bn[nn];
                }
            }
        }
    }
    float bv[4];
    #pragma unroll
    for (int nn=0;nn<4;++nn){ int gn = n_blk + tn + nn; bv[nn] = ba[gn] + bb[gn]; }
    #pragma unroll
    for (int mm = 0; mm < 8; ++mm){
        int gm = m_blk + tm + mm;
        *(float4*)(C + (size_t)gm*G4 + n_blk + tn) =
            make_float4(acc[mm][0]+bv[0], acc[mm][1]+bv[1], acc[mm][2]+bv[2], acc[mm][3]+bv[3]);
    }
}

// ---------------------------------------------------------------- direction-interleaved LSTM
// 8 teams of 32 wgs; team = batch-pair (2 batches), BOTH directions per wg.
// wg rank owns hidden [rank*16,+16) for fwd AND bwd: 256 weight VGPRs (fully
// unrolled). Per iteration: poll+stage fwd -> issue bwd poll loads (prefetch in
// flight) -> compute fwd -> act/store fwd -> check bwd (landed during fwd
// compute) -> compute bwd -> act/store bwd. Each chain's LLC round-trip hides
// under the other chain's compute (R7 showed ~7k cyc/step of exposed wait).
// Exchange: packed u64 (tag<<32|float_bits) relaxed agent atomics, double-
// buffered by parity; hteam layout [team][dir][par][b*512 + k].
__global__ __launch_bounds__(256, 1) void lstm_k(const float* __restrict__ xwf,
                                                 const float* __restrict__ xwb,
                                                 const float* __restrict__ whhf,
                                                 const float* __restrict__ whhb,
                                                 unsigned long long* __restrict__ hteam, // 8*2*2*1024 u64
                                                 float* __restrict__ hf_all,
                                                 float* __restrict__ hb_all)
{
    __shared__ __align__(16) float h_sf[2*HD];     // 4 KB
    __shared__ __align__(16) float h_sb[2*HD];     // 4 KB
    __shared__ __align__(16) float part[8*128];    // 4 KB [kc][row*2+b]
    __shared__ float gates_s[128];                 // [row*2+b]
    __shared__ float cst[64];                      // [dir*32 + hid*2 + b]
    const int wg   = blockIdx.x;
    const int team = wg >> 5;
    const int rank = wg & 31;
    const int b0   = team * 2;
    const int t    = threadIdx.x;
    const int wv   = t >> 6;
    const int lane = t & 63;
    const int rg   = t & 31;
    const int kc   = t >> 5;                       // 0..7 (64 k each)
    const int lr0  = rg*2, lr1 = rg*2 + 1;
    const int grow0 = (lr0 >> 4)*HD + rank*16 + (lr0 & 15);
    const int grow1 = (lr1 >> 4)*HD + rank*16 + (lr1 & 15);
    unsigned long long* hTf = hteam + (size_t)(team*2 + 0)*2*1024;
    unsigned long long* hTb = hteam + (size_t)(team*2 + 1)*2*1024;

    // ---- one-time: both dirs' weight slices into registers (64 float4 = 256 VGPRs) ----
    float4 wf0[16], wf1[16], wb0[16], wb1[16];
    {
        const float* p0 = whhf + (size_t)grow0*HD + kc*64;
        const float* p1 = whhf + (size_t)grow1*HD + kc*64;
        const float* p2 = whhb + (size_t)grow0*HD + kc*64;
        const float* p3 = whhb + (size_t)grow1*HD + kc*64;
        #pragma unroll
        for (int q = 0; q < 16; ++q){
            wf0[q] = *(const float4*)(p0 + q*4);
            wf1[q] = *(const float4*)(p1 + q*4);
            wb0[q] = *(const float4*)(p2 + q*4);
            wb1[q] = *(const float4*)(p3 + q*4);
        }
    }
    // reduce mapping (t<128): entry = row*2 + b
    const int rrow = t >> 1, rb2 = t & 1;
    const int growr = (rrow >> 4)*HD + rank*16 + (rrow & 15);
    // activation mapping (t<32)
    const int ahl = t >> 1, ab2 = t & 1;
    const int hidx_a = rank*16 + ahl;
    // staging slots (4 u64/thread/dir): b in {0,1}, halves {0,64}
    const int s0 = wv*128 + lane;

    if (t < 64) cst[t] = 0.f;
    __syncthreads();

    int par = 0;
    for (int s = 0; s < SL; ++s){
        float xval_f = 0.f, xval_b = 0.f;
        if (t < 128){
            xval_f = xwf[(size_t)((b0 + rb2)*SL + s)*G4 + growr];
            xval_b = xwb[(size_t)((b0 + rb2)*SL + (SL-1 - s))*G4 + growr];
        }
        // ---- 1. poll + stage fwd (expected ready: stored ~half iteration ago) ----
        {
            const unsigned long long* src = hTf + (size_t)par*1024;
            unsigned long long v0,v1,v2,v3;
            const unsigned want = (unsigned)s;
            for (;;){
                v0 = __hip_atomic_load(&src[      s0     ], __ATOMIC_RELAXED, __HIP_MEMORY_SCOPE_AGENT);
                v1 = __hip_atomic_load(&src[      s0 + 64], __ATOMIC_RELAXED, __HIP_MEMORY_SCOPE_AGENT);
                v2 = __hip_atomic_load(&src[512 + s0     ], __ATOMIC_RELAXED, __HIP_MEMORY_SCOPE_AGENT);
                v3 = __hip_atomic_load(&src[512 + s0 + 64], __ATOMIC_RELAXED, __HIP_MEMORY_SCOPE_AGENT);
                if (((unsigned)(v0>>32)==want) & ((unsigned)(v1>>32)==want) &
                    ((unsigned)(v2>>32)==want) & ((unsigned)(v3>>32)==want)) break;
                __builtin_amdgcn_s_sleep(1);
            }
            h_sf[     s0     ] = __uint_as_float((unsigned)v0);
            h_sf[     s0 + 64] = __uint_as_float((unsigned)v1);
            h_sf[HD + s0     ] = __uint_as_float((unsigned)v2);
            h_sf[HD + s0 + 64] = __uint_as_float((unsigned)v3);
        }
        // ---- 2. issue bwd poll loads (in flight during fwd compute) ----
        const unsigned long long* srcb = hTb + (size_t)par*1024;
        unsigned long long p0 = __hip_atomic_load(&srcb[      s0     ], __ATOMIC_RELAXED, __HIP_MEMORY_SCOPE_AGENT);
        unsigned long long p1 = __hip_atomic_load(&srcb[      s0 + 64], __ATOMIC_RELAXED, __HIP_MEMORY_SCOPE_AGENT);
        unsigned long long p2 = __hip_atomic_load(&srcb[512 + s0     ], __ATOMIC_RELAXED, __HIP_MEMORY_SCOPE_AGENT);
        unsigned long long p3 = __hip_atomic_load(&srcb[512 + s0 + 64], __ATOMIC_RELAXED, __HIP_MEMORY_SCOPE_AGENT);
        // ---- 3. fwd partials: 2 rows x 2 batches x 64 k ----
        {
            float a00=0.f,a01=0.f,a10=0.f,a11=0.f;
            #pragma unroll
            for (int q = 0; q < 16; ++q){
                float4 wa = wf0[q], wb = wf1[q];
                float4 h0 = *(const float4*)(h_sf + 0*HD + kc*64 + q*4);
                float4 h1 = *(const float4*)(h_sf + 1*HD + kc*64 + q*4);
                a00 += wa.x*h0.x + wa.y*h0.y + wa.z*h0.z + wa.w*h0.w;
                a01 += wa.x*h1.x + wa.y*h1.y + wa.z*h1.z + wa.w*h1.w;
                a10 += wb.x*h0.x + wb.y*h0.y + wb.z*h0.z + wb.w*h0.w;
                a11 += wb.x*h1.x + wb.y*h1.y + wb.z*h1.z + wb.w*h1.w;
            }
            *(float4*)&part[kc*128 + lr0*2] = make_float4(a00,a01,a10,a11);
        }
        __syncthreads();
        if (t < 128){
            float g = 0.f;
            #pragma unroll
            for (int c = 0; c < 8; ++c) g += part[c*128 + t];
            gates_s[t] = g + xval_f;
        }
        __syncthreads();
        if (t < 32){
            float gi = gates_s[(0*16 + ahl)*2 + ab2];
            float gf = gates_s[(1*16 + ahl)*2 + ab2];
            float gc = gates_s[(2*16 + ahl)*2 + ab2];
            float go_ = gates_s[(3*16 + ahl)*2 + ab2];
            float cp = cst[t];
            float cn = sigf(gf)*cp + sigf(gi)*tanhf(gc);
            float hn = sigf(go_)*tanhf(cn);
            cst[t] = cn;
            unsigned long long pk = ((unsigned long long)(unsigned)(s+1) << 32)
                                  | (unsigned long long)__float_as_uint(hn);
            __hip_atomic_store(&hTf[(size_t)(par^1)*1024 + ab2*512 + hidx_a], pk,
                               __ATOMIC_RELAXED, __HIP_MEMORY_SCOPE_AGENT);
            hf_all[(size_t)((b0 + ab2)*SL + s)*HD + hidx_a] = hn;
        }
        // ---- 4. check/stage bwd (prefetched; spin only on miss) ----
        {
            const unsigned want = (unsigned)s;
            if (!(((unsigned)(p0>>32)==want) & ((unsigned)(p1>>32)==want) &
                  ((unsigned)(p2>>32)==want) & ((unsigned)(p3>>32)==want))){
                for (;;){
                    p0 = __hip_atomic_load(&srcb[      s0     ], __ATOMIC_RELAXED, __HIP_MEMORY_SCOPE_AGENT);
                    p1 = __hip_atomic_load(&srcb[      s0 + 64], __ATOMIC_RELAXED, __HIP_MEMORY_SCOPE_AGENT);
                    p2 = __hip_atomic_load(&srcb[512 + s0     ], __ATOMIC_RELAXED, __HIP_MEMORY_SCOPE_AGENT);
                    p3 = __hip_atomic_load(&srcb[512 + s0 + 64], __ATOMIC_RELAXED, __HIP_MEMORY_SCOPE_AGENT);
                    if (((unsigned)(p0>>32)==want) & ((unsigned)(p1>>32)==want) &
                        ((unsigned)(p2>>32)==want) & ((unsigned)(p3>>32)==want)) break;
                    __builtin_amdgcn_s_sleep(1);
                }
            }
            h_sb[     s0     ] = __uint_as_float((unsigned)p0);
            h_sb[     s0 + 64] = __uint_as_float((unsigned)p1);
            h_sb[HD + s0     ] = __uint_as_float((unsigned)p2);
            h_sb[HD + s0 + 64] = __uint_as_float((unsigned)p3);
        }
        // ---- 5. bwd partials ----
        {
            float a00=0.f,a01=0.f,a10=0.f,a11=0.f;
            #pragma unroll
            for (int q = 0; q < 16; ++q){
                float4 wa = wb0[q], wb = wb1[q];
                float4 h0 = *(const float4*)(h_sb + 0*HD + kc*64 + q*4);
                float4 h1 = *(const float4*)(h_sb + 1*HD + kc*64 + q*4);
                a00 += wa.x*h0.x + wa.y*h0.y + wa.z*h0.z + wa.w*h0.w;
                a01 += wa.x*h1.x + wa.y*h1.y + wa.z*h1.z + wa.w*h1.w;
                a10 += wb.x*h0.x + wb.y*h0.y + wb.z*h0.z + wb.w*h0.w;
                a11 += wb.x*h1.x + wb.y*h1.y + wb.z*h1.z + wb.w*h1.w;
            }
            *(float4*)&part[kc*128 + lr0*2] = make_float4(a00,a01,a10,a11);
        }
        __syncthreads();
        if (t < 128){
            float g = 0.f;
            #pragma unroll
            for (int c = 0; c < 8; ++c) g += part[c*128 + t];
            gates_s[t] = g + xval_b;
        }
        __syncthreads();
        if (t < 32){
            float gi = gates_s[(0*16 + ahl)*2 + ab2];
            float gf = gates_s[(1*16 + ahl)*2 + ab2];
            float gc = gates_s[(2*16 + ahl)*2 + ab2];
            float go_ = gates_s[(3*16 + ahl)*2 + ab2];
            float cp = cst[32 + t];
            float cn = sigf(gf)*cp + sigf(gi)*tanhf(gc);
            float hn = sigf(go_)*tanhf(cn);
            cst[32 + t] = cn;
            unsigned long long pk = ((unsigned long long)(unsigned)(s+1) << 32)
                                  | (unsigned long long)__float_as_uint(hn);
            __hip_atomic_store(&hTb[(size_t)(par^1)*1024 + ab2*512 + hidx_a], pk,
                               __ATOMIC_RELAXED, __HIP_MEMORY_SCOPE_AGENT);
            hb_all[(size_t)((b0 + ab2)*SL + (SL-1 - s))*HD + hidx_a] = hn;
        }
        par ^= 1;
    }
}

// ---------------------------------------------------------------- combine o | bio_emb
__global__ __launch_bounds__(256) void combine_k(const float* __restrict__ hf,
                                                 const float* __restrict__ hb,
                                                 const int* __restrict__ bio_gold,
                                                 const float* __restrict__ bio_emb,
                                                 float* __restrict__ oc)
{
    int idx = blockIdx.x*256 + threadIdx.x;
    if (idx >= NTOK*144) return;
    int row = idx / 144;
    int c4 = (idx - row*144) * 4;
    float4 v;
    if (c4 < HD){
        float4 a = *(const float4*)(hf + (size_t)row*HD + c4);
        float4 b = *(const float4*)(hb + (size_t)row*HD + c4);
        v = make_float4(0.5f*(a.x+b.x), 0.5f*(a.y+b.y), 0.5f*(a.z+b.z), 0.5f*(a.w+b.w));
    } else {
        int bg = bio_gold[row];
        v = *(const float4*)(bio_emb + bg*BE + (c4 - HD));
    }
    *(float4*)(oc + (size_t)row*OCD + c4) = v;
}

// ---------------------------------------------------------------- CRF NLL (wave-sync) + msum
__global__ __launch_bounds__(64) void crf_k(const float* __restrict__ emi,
                                            const int* __restrict__ tags,
                                            const int* __restrict__ tokens,
                                            const float* __restrict__ trans,
                                            const float* __restrict__ startv,
                                            const float* __restrict__ endv,
                                            float* __restrict__ out_crf,
                                            float* __restrict__ out_m)
{
    const int b = blockIdx.x, lane = threadIdx.x;
    unsigned long long m0 = __ballot(tokens[b*SL + lane] != 0);
    unsigned long long m1 = __ballot(tokens[b*SL + 64 + lane] != 0);
    const int len = __popcll(m0) + __popcll(m1);
    float npart = 0.f;
    #pragma unroll
    for (int half = 0; half < 2; ++half){
        int tt = lane + half*64;
        if (tt >= 1 && tt < len){
            int tp = tags[b*SL + tt - 1], tc = tags[b*SL + tt];
            npart += trans[tp*NT + tc] + emi[(size_t)(b*SL + tt)*NT + tc];
        }
    }
    #pragma unroll
    for (int off = 32; off > 0; off >>= 1) npart += __shfl_down(npart, off);
    float tr[NT]; float alpha = -1e30f;
    if (lane < NT){
        #pragma unroll
        for (int i = 0; i < NT; ++i) tr[i] = trans[i*NT + lane];
        alpha = startv[lane] + emi[(size_t)(b*SL)*NT + lane];
    }
    for (int tt = 1; tt < SL; ++tt){
        float al[NT];
        #pragma unroll
        for (int i = 0; i < NT; ++i) al[i] = __shfl(alpha, i);
        if (lane < NT && tt < len){
            float mx = -1e30f;
            #pragma unroll
            for (int i = 0; i < NT; ++i) mx = fmaxf(mx, al[i] + tr[i]);
            float se = 0.f;
            #pragma unroll
            for (int i = 0; i < NT; ++i) se += __expf(al[i] + tr[i] - mx);
            alpha = mx + __logf(se) + emi[(size_t)(b*SL + tt)*NT + lane];
        }
    }
    float alf = (lane < NT) ? (alpha + endv[lane]) : -1e30f;
    float alE[NT];
    #pragma unroll
    for (int i = 0; i < NT; ++i) alE[i] = __shfl(alf, i);
    if (lane == 0){
        float mx = -1e30f;
        #pragma unroll
        for (int i = 0; i < NT; ++i) mx = fmaxf(mx, alE[i]);
        float se = 0.f;
        #pragma unroll
        for (int i = 0; i < NT; ++i) se += __expf(alE[i] - mx);
        float den = mx + __logf(se);
        int t0g = tags[b*SL];
        float num = startv[t0g] + emi[(size_t)(b*SL)*NT + t0g] + npart;
        num += endv[tags[b*SL + len - 1]];
        atomicAdd(out_crf, -(num - den) * (1.0f/16.0f));
        atomicAdd(out_m, (float)len);
    }
}

// ---------------------------------------------------------------- fused uv->logits->BCE
__global__ __launch_bounds__(256) void sel_k(const float* __restrict__ U2,
                                             const float* __restrict__ V2,
                                             const float* __restrict__ uvb,
                                             const float* __restrict__ rel_emb,
                                             const int* __restrict__ gold,
                                             const int* __restrict__ tokens,
                                             float* __restrict__ out_sel)
{
    __shared__ float ret_s[RE][52];
    __shared__ float pt_s[RE][68];
    __shared__ float vb_s[RE];
    __shared__ float mk_s[64];
    __shared__ float red_s[4];
    const int jt = blockIdx.x, qi = blockIdx.y, b = blockIdx.z;
    const int t = threadIdx.x;
    if (tokens[b*SL + qi] == 0) return;
    if (t < 32){
        float4 v4 = *(const float4*)(V2 + (size_t)(b*SL + qi)*RE + t*4);
        float4 b4 = *(const float4*)(uvb + t*4);
        vb_s[t*4+0] = v4.x + b4.x; vb_s[t*4+1] = v4.y + b4.y;
        vb_s[t*4+2] = v4.z + b4.z; vb_s[t*4+3] = v4.w + b4.w;
    }
    if (t < 64) mk_s[t] = (tokens[b*SL + jt*64 + t] != 0) ? 1.f : 0.f;
    {
        int r = t & 63;
        for (int q = t >> 6; q < 32; q += 4){
            if (r < NR){
                float4 e4 = *(const float4*)(rel_emb + (size_t)r*RE + q*4);
                ret_s[q*4+0][r] = e4.x; ret_s[q*4+1][r] = e4.y;
                ret_s[q*4+2][r] = e4.z; ret_s[q*4+3][r] = e4.w;
            } else if (r < 64){
                ret_s[q*4+0][r] = 0.f; ret_s[q*4+1][r] = 0.f;
                ret_s[q*4+2][r] = 0.f; ret_s[q*4+3][r] = 0.f;
            }
        }
    }
    __syncthreads();
    {
        int j = t & 63;
        for (int q = t >> 6; q < 32; q += 4){
            float4 u4 = *(const float4*)(U2 + (size_t)(b*SL + jt*64 + j)*RE + q*4);
            pt_s[q*4+0][j] = fmaxf(u4.x + vb_s[q*4+0], 0.f);
            pt_s[q*4+1][j] = fmaxf(u4.y + vb_s[q*4+1], 0.f);
            pt_s[q*4+2][j] = fmaxf(u4.z + vb_s[q*4+2], 0.f);
            pt_s[q*4+3][j] = fmaxf(u4.w + vb_s[q*4+3], 0.f);
        }
    }
    __syncthreads();
    const int mj = (t & 15) * 4;
    const int nr = (t >> 4) * 4;
    float accv[4][4];
    #pragma unroll
    for (int i=0;i<4;++i){ accv[i][0]=0.f; accv[i][1]=0.f; accv[i][2]=0.f; accv[i][3]=0.f; }
    #pragma unroll 4
    for (int k = 0; k < RE; ++k){
        float4 aj = *(const float4*)&pt_s[k][mj];
        float4 br = *(const float4*)&ret_s[k][nr];
        float am[4] = {aj.x, aj.y, aj.z, aj.w};
        float bn[4] = {br.x, br.y, br.z, br.w};
        #pragma unroll
        for (int mm = 0; mm < 4; ++mm){
            #pragma unroll
            for (int nn = 0; nn < 4; ++nn)
                accv[mm][nn] += am[mm]*bn[nn];
        }
    }
    float lsum = 0.f;
    #pragma unroll
    for (int nn = 0; nn < 4; ++nn){
        int r = nr + nn;
        if (r < NR){
            const int* gp = gold + (size_t)((b*SL + qi)*NR + r)*SL + jt*64 + mj;
            #pragma unroll
            for (int mm = 0; mm < 4; ++mm){
                float l = accv[mm][nn];
                float g = (float)gp[mm];
                float bce = fmaxf(l, 0.f) - l*g + __logf(1.f + __expf(-fabsf(l)));
                lsum += bce * mk_s[mj + mm];
            }
        }
    }
    #pragma unroll
    for (int off = 32; off > 0; off >>= 1) lsum += __shfl_down(lsum, off);
    if ((t & 63) == 0) red_s[t >> 6] = lsum;
    __syncthreads();
    if (t == 0) atomicAdd(out_sel, red_s[0]+red_s[1]+red_s[2]+red_s[3]);
}

// ---------------------------------------------------------------- finalize
__global__ void finalize_k(const float* __restrict__ accum, float* __restrict__ out)
{
    if (threadIdx.x == 0 && blockIdx.x == 0) out[0] = accum[0] + accum[1] / accum[2];
}

// ---------------------------------------------------------------- launch
extern "C" void kernel_launch(void* const* d_in, const int* in_sizes, int n_in,
                              void* d_out, int out_size, void* d_ws, size_t ws_size,
                              hipStream_t stream)
{
    const int*   tokens    = (const int*)  d_in[0];
    const int*   bio_gold  = (const int*)  d_in[1];
    const int*   sel_gold  = (const int*)  d_in[2];
    const float* word_emb  = (const float*)d_in[4];
    const float* rel_emb   = (const float*)d_in[5];
    const float* bio_emb   = (const float*)d_in[6];
    const float* w_ih_f    = (const float*)d_in[7];
    const float* w_hh_f    = (const float*)d_in[8];
    const float* b_ih_f    = (const float*)d_in[9];
    const float* b_hh_f    = (const float*)d_in[10];
    const float* w_ih_b    = (const float*)d_in[11];
    const float* w_hh_b    = (const float*)d_in[12];
    const float* b_ih_b    = (const float*)d_in[13];
    const float* b_hh_b    = (const float*)d_in[14];
    const float* emission_w= (const float*)d_in[15];
    const float* emission_b= (const float*)d_in[16];
    const float* sel_u_w   = (const float*)d_in[17];
    const float* sel_u_b   = (const float*)d_in[18];
    const float* sel_v_w   = (const float*)d_in[19];
    const float* sel_v_b   = (const float*)d_in[20];
    const float* sel_uv_w  = (const float*)d_in[21];
    const float* sel_uv_b  = (const float*)d_in[22];
    const float* crf_trans = (const float*)d_in[23];
    const float* crf_start = (const float*)d_in[24];
    const float* crf_end   = (const float*)d_in[25];
    (void)in_sizes; (void)n_in; (void)out_size; (void)ws_size;

    float* ws     = (float*)d_ws;
    float* emb    = ws;                         // region reused for hteam
    float* xwf    = emb    + (size_t)NTOK*ED;
    float* xwb    = xwf    + (size_t)NTOK*G4;
    float* hf_all = xwb    + (size_t)NTOK*G4;
    float* hb_all = hf_all + (size_t)NTOK*HD;
    float* oc     = hb_all + (size_t)NTOK*HD;
    float* emi    = oc     + (size_t)NTOK*OCD;
    float* u_     = emi    + (size_t)NTOK*NT;
    float* v_     = u_     + (size_t)NTOK*RE;
    float* U2     = v_     + (size_t)NTOK*RE;
    float* V2     = U2     + (size_t)NTOK*RE;
    float* accum  = V2     + (size_t)NTOK*RE;   // [0]=crf, [1]=sel_sum, [2]=msum, [3]=pad

    // packed h exchange: 8 teams x 2 dirs x 2 parities x 1024 u64 = 256 KB
    unsigned long long* hteam = (unsigned long long*)emb;

    hipMemsetAsync(accum, 0, 4*sizeof(float), stream);
    hipMemsetAsync(hteam, 0, (size_t)8*2*2*1024*sizeof(unsigned long long), stream);

    // fused gather + xW GEMM, both directions in one dispatch
    gemm_emb_k<<<dim3(NTOK/128, G4/64, 2), 256, 0, stream>>>(tokens, word_emb,
                                                             w_ih_f, w_ih_b, xwf, xwb,
                                                             b_ih_f, b_hh_f, b_ih_b, b_hh_b);

    {
        const float *p_xwf = xwf, *p_xwb = xwb, *p_whf = w_hh_f, *p_whb = w_hh_b;
        unsigned long long* p_ht = hteam;
        float *p_hf = hf_all, *p_hb = hb_all;
        void* args[7] = {&p_xwf, &p_xwb, &p_whf, &p_whb, &p_ht, &p_hf, &p_hb};
        hipLaunchCooperativeKernel(lstm_k, dim3(256), dim3(256), args, 0u, stream);
    }

    combine_k<<<(NTOK*144 + 255)/256, 256, 0, stream>>>(hf_all, hb_all, bio_gold, bio_emb, oc);

    gemm_k<64><<<dim3(NTOK/64, 1), 256, 0, stream>>>(oc, OCD, emission_w, HD, emi, NT, NT, HD, emission_b, nullptr, 0);
    gemm_dual_k<64><<<dim3(NTOK/64, 2, 2), 256, 0, stream>>>(oc, oc, OCD, sel_u_w, sel_v_w, OCD,
                                                             u_, v_, RE, RE, OCD, sel_u_b, sel_v_b, 1);
    gemm_dual_k<64><<<dim3(NTOK/64, 2, 2), 256, 0, stream>>>(u_, v_, RE, sel_uv_w, sel_uv_w + RE, 2*RE,
                                                             U2, V2, RE, RE, RE, nullptr, nullptr, 0);

    crf_k<<<NB, 64, 0, stream>>>(emi, bio_gold, tokens, crf_trans, crf_start, crf_end, accum + 0, accum + 2);
    sel_k<<<dim3(2, SL, NB), 256, 0, stream>>>(U2, V2, sel_uv_b, rel_emb, sel_gold, tokens, accum + 1);

    finalize_k<<<1, 1, 0, stream>>>(accum, (float*)d_out);
}